// Round 15
// baseline (9816.434 us; speedup 1.0000x reference)
//
#include <hip/hip_runtime.h>
#include <math.h>

// ---------------------------------------------------------------------------
// TreeTextEmbed — numpy-faithful fp32 pipeline, round 15.
// NUMERICS FROZEN (r7-r14 passed, absmax 0.015625): ascending-k fp32 FMA chain
// w/ 384/128 panels; AVX512 pairwise mean; baseline-SSE einsum; __f*_rn
// elementwise in np op order.
// PERF vs r13 (GEMM LDS-BW bound at 4 FLOP/LDS-byte):
//   - GEMM split into two passes at the FROZEN panel boundary k=384:
//     pass A writes raw P1; pass B computes P2 and does
//     v = fadd32(fadd32(P1, P2), bias) [+ gate] in-place. Halved live
//     accumulators enable 8x8 per-thread tiles with 64x64 SQUARE wave-tiles:
//     16 FLOP/LDS-byte (wave reads 8KB W + 8KB X per tile for 131K FMAs).
//   - BM=128, BN=256, BK=32, 512 thr. W staged via gload_lds (linear LDS);
//     X staged via 2 reg-f4 + ds_write into padded [128][36] rows
//     (conflict-free reads; gload_lds can't target padded layouts).
//   - Raw s_barrier + counted waits; lgkmcnt(0) before post-ds_write barrier.
// ---------------------------------------------------------------------------

__device__ __forceinline__ float fadd32(float a, float b) { return __fadd_rn(a, b); }
__device__ __forceinline__ float fmul32(float a, float b) { return __fmul_rn(a, b); }
__device__ __forceinline__ float fsub32(float a, float b) { return __fsub_rn(a, b); }
__device__ __forceinline__ float fdiv32(float a, float b) { return __fdiv_rn(a, b); }

// async global->LDS, 16B per lane; LDS dest = wave-uniform base + lane*16
__device__ __forceinline__ void gload16(const float* g, float* l) {
  __builtin_amdgcn_global_load_lds(
      (const __attribute__((address_space(1))) void*)g,
      (__attribute__((address_space(3))) void*)l, 16, 0, 0);
}

// numpy pairwise sum of contiguous 512 floats, AVX512 model (bit-frozen).
__device__ __forceinline__ float np_pairwise512(const float* row, int lane) {
  const int L = lane >> 4, j = lane & 15;
  const float* p = row + 128 * L + j;
  const float r0 = p[0],  r1 = p[16], r2 = p[32],  r3 = p[48];
  const float r4 = p[64], r5 = p[80], r6 = p[96],  r7 = p[112];
  float v = fadd32(fadd32(fadd32(r0, r1), fadd32(r2, r3)),
                   fadd32(fadd32(r4, r5), fadd32(r6, r7)));
  v = fadd32(v, __shfl_xor(v, 8));
  v = fadd32(v, __shfl_xor(v, 4));
  v = fadd32(v, __shfl_xor(v, 2));
  v = fadd32(v, __shfl_xor(v, 1));
  v = fadd32(v, __shfl_xor(v, 16));
  v = fadd32(v, __shfl_xor(v, 32));
  return v;
}

// ---------------- K1: embed + LN + pool2 (float4; per-element ops frozen) ----
__global__ __launch_bounds__(256) void k_embed(
    const int* __restrict__ text, const float* __restrict__ pe,
    const float* __restrict__ id_w, const float* __restrict__ id_b,
    const float* __restrict__ eg, const float* __restrict__ eb,
    float* __restrict__ fused) {
  __shared__ float rb[4][512];
  const int w = threadIdx.x >> 6;
  const int lane = threadIdx.x & 63;
  const int wid = blockIdx.x * 4 + w;  // row b*2048+t
  const int b = wid >> 11;
  const int t = wid & 2047;
  const int c0 = lane * 4, c1 = 256 + lane * 4;
  const float4 iw0 = *(const float4*)&id_w[c0], iw1 = *(const float4*)&id_w[c1];
  const float4 ib0 = *(const float4*)&id_b[c0], ib1 = *(const float4*)&id_b[c1];
  const float4 g0  = *(const float4*)&eg[c0],  g1  = *(const float4*)&eg[c1];
  const float4 e0  = *(const float4*)&eb[c0],  e1  = *(const float4*)&eb[c1];
  float4 fus0, fus1;
#pragma unroll
  for (int ss = 0; ss < 2; ++ss) {
    const int s = 2 * t + ss;
    const float idv = (float)text[b * 4096 + s];
    const float4 p0 = *(const float4*)&pe[(size_t)s * 512 + c0];
    const float4 p1 = *(const float4*)&pe[(size_t)s * 512 + c1];
    float4 x0, x1;
#pragma unroll
    for (int j = 0; j < 4; ++j) {
      (&x0.x)[j] = fadd32(fadd32(fmul32(idv, (&iw0.x)[j]), (&ib0.x)[j]), (&p0.x)[j]);
      (&x1.x)[j] = fadd32(fadd32(fmul32(idv, (&iw1.x)[j]), (&ib1.x)[j]), (&p1.x)[j]);
    }
    *(float4*)&rb[w][c0] = x0;
    *(float4*)&rb[w][c1] = x1;
    const float m = fmul32(np_pairwise512(rb[w], lane), 1.f / 512.f);
    float4 d0, d1, q0, q1;
#pragma unroll
    for (int j = 0; j < 4; ++j) {
      (&d0.x)[j] = fsub32((&x0.x)[j], m);
      (&d1.x)[j] = fsub32((&x1.x)[j], m);
      (&q0.x)[j] = fmul32((&d0.x)[j], (&d0.x)[j]);
      (&q1.x)[j] = fmul32((&d1.x)[j], (&d1.x)[j]);
    }
    *(float4*)&rb[w][c0] = q0;
    *(float4*)&rb[w][c1] = q1;
    const float var = fmul32(np_pairwise512(rb[w], lane), 1.f / 512.f);
    const float sdev = __fsqrt_rn(fadd32(var, 1e-5f));
#pragma unroll
    for (int j = 0; j < 4; ++j) {
      const float l0 = fadd32(fmul32(fdiv32((&d0.x)[j], sdev), (&g0.x)[j]), (&e0.x)[j]);
      const float l1 = fadd32(fmul32(fdiv32((&d1.x)[j], sdev), (&g1.x)[j]), (&e1.x)[j]);
      if (ss) {
        (&fus0.x)[j] = fmul32(fadd32((&fus0.x)[j], l0), 0.5f);
        (&fus1.x)[j] = fmul32(fadd32((&fus1.x)[j], l1), 0.5f);
      } else {
        (&fus0.x)[j] = l0;
        (&fus1.x)[j] = l1;
      }
    }
  }
  const size_t row = (size_t)wid * 512;
  *(float4*)&fused[row + c0] = fus0;
  *(float4*)&fused[row + c1] = fus1;
}

// ---------------- tiled weight transpose: WT[k][n] = W[n][k], K=512 ----------
__global__ __launch_bounds__(256) void k_transpose_w(
    const float* __restrict__ W, float* __restrict__ WT, int Nn) {
  __shared__ float t[32][33];
  const int n0 = blockIdx.x * 32, k0 = blockIdx.y * 32;
  const int li = threadIdx.x & 31, wi = threadIdx.x >> 5;
  for (int r = wi; r < 32; r += 8)
    t[r][li] = W[(size_t)(n0 + r) * 512 + k0 + li];
  __syncthreads();
  for (int r = wi; r < 32; r += 8)
    WT[(size_t)(k0 + r) * Nn + n0 + li] = t[li][r];
}

// ---- split-panel np-sgemm from WT[K][N], square wave-tiles.
// BM=128, BN=256, BK=32; 512 thr (8 waves); wave = 64x64; thread = 8x8.
// rows: wrow*64 + lr + 8r ; cols: wcol*64 + lc*8 + c.
// pass A (final=0): OUT = P1 (raw chain k0..k0+ntiles*32).
// pass B (final=1): OUT = [gate]( fadd32(fadd32(P1, P2), bias) )  (bit-frozen).
__global__ __launch_bounds__(512) void k_gemm_sq(
    const float* __restrict__ X, const float* __restrict__ WT,
    const float* __restrict__ bias, const float* __restrict__ th,
    float* __restrict__ OUT, int N, int k0start, int ntiles, int finalpass) {
  __shared__ float Xs[2][128][36];   // 36.9 KB, padded rows (conflict-free)
  __shared__ float Ws[2][32][256];   // 64 KB, linear for gload_lds
  const int tid = threadIdx.x;
  const int lane = tid & 63;
  const int wv = tid >> 6;
  const int wrow = wv >> 2, wcol = wv & 3;
  const int lr = lane >> 3, lc = lane & 7;
  const int rbase = wrow * 64 + lr;        // + 8*r
  const int cbase = wcol * 64 + lc * 8;    // 8 cols
  const size_t bm = (size_t)blockIdx.x * 128;
  const int bn = blockIdx.y * 256;
  // X staging mapping: 2 f4/thread; id = tid*2+i -> row=id>>3, kq=(id&7)*4
  const int xrow = tid >> 2;               // (tid*2)>>3
  const int xkq = (tid & 3) * 8;           // ((tid*2)&7)*4 ; second f4 at +4

  float acc[8][8];
#pragma unroll
  for (int r = 0; r < 8; ++r)
#pragma unroll
    for (int c = 0; c < 8; ++c) acc[r][c] = 0.f;

  float4 xs0, xs1;
#define SQ_ISSUE(k0)                                                          \
  {                                                                           \
    xs0 = *(const float4*)&X[(bm + xrow) * 512 + (k0) + xkq];                 \
    xs1 = *(const float4*)&X[(bm + xrow) * 512 + (k0) + xkq + 4];             \
    _Pragma("unroll")                                                         \
    for (int c = 0; c < 4; ++c)                                               \
      gload16(&WT[(size_t)((k0) + wv * 4 + c) * N + bn + lane * 4],           \
              &Ws[buf_][wv * 4 + c][0]);                                      \
  }
#define SQ_XWRITE(bufw)                                                       \
  {                                                                           \
    *(float4*)&Xs[bufw][xrow][xkq] = xs0;                                     \
    *(float4*)&Xs[bufw][xrow][xkq + 4] = xs1;                                 \
  }
#define SQ_COMPUTE(bufc)                                                      \
  _Pragma("unroll")                                                           \
  for (int kq = 0; kq < 32; kq += 4) {                                        \
    float4 wq[8];                                                             \
    _Pragma("unroll")                                                         \
    for (int u = 0; u < 4; ++u) {                                             \
      wq[2 * u]     = *(const float4*)&Ws[bufc][kq + u][cbase];               \
      wq[2 * u + 1] = *(const float4*)&Ws[bufc][kq + u][cbase + 4];           \
    }                                                                         \
    _Pragma("unroll")                                                         \
    for (int r = 0; r < 8; ++r) {                                             \
      const float4 xf = *(const float4*)&Xs[bufc][rbase + 8 * r][kq];         \
      _Pragma("unroll")                                                       \
      for (int u = 0; u < 4; ++u) {                                           \
        const float xv = (&xf.x)[u];                                          \
        acc[r][0] = __fmaf_rn(xv, wq[2 * u].x, acc[r][0]);                    \
        acc[r][1] = __fmaf_rn(xv, wq[2 * u].y, acc[r][1]);                    \
        acc[r][2] = __fmaf_rn(xv, wq[2 * u].z, acc[r][2]);                    \
        acc[r][3] = __fmaf_rn(xv, wq[2 * u].w, acc[r][3]);                    \
        acc[r][4] = __fmaf_rn(xv, wq[2 * u + 1].x, acc[r][4]);                \
        acc[r][5] = __fmaf_rn(xv, wq[2 * u + 1].y, acc[r][5]);                \
        acc[r][6] = __fmaf_rn(xv, wq[2 * u + 1].z, acc[r][6]);                \
        acc[r][7] = __fmaf_rn(xv, wq[2 * u + 1].w, acc[r][7]);                \
      }                                                                       \
    }                                                                         \
  }

  {  // prologue: stage tile 0 into buf 0
    const int buf_ = 0;
    SQ_ISSUE(k0start);
    SQ_XWRITE(0);  // compiler inserts vmcnt wait for xs regs
    asm volatile("s_waitcnt vmcnt(0)" ::: "memory");      // W landed
    asm volatile("s_waitcnt lgkmcnt(0)" ::: "memory");    // X writes done
    asm volatile("s_barrier" ::: "memory");
  }
  for (int t = 0; t < ntiles; ++t) {
    const int cur = t & 1;
    if (t < ntiles - 1) {
      const int buf_ = cur ^ 1;
      SQ_ISSUE(k0start + (t + 1) * 32);   // 6 vmem ops stay in flight
    }
    SQ_COMPUTE(cur);
    asm volatile("s_barrier" ::: "memory");               // reads of cur done
    if (t < ntiles - 1) {
      SQ_XWRITE(cur ^ 1);                                 // waits xs vmcnt only
      asm volatile("s_waitcnt vmcnt(0)" ::: "memory");    // W(nxt) landed (overlapped)
      asm volatile("s_waitcnt lgkmcnt(0)" ::: "memory");  // X writes visible
      asm volatile("s_barrier" ::: "memory");
    }
  }
  // epilogue
#pragma unroll
  for (int r = 0; r < 8; ++r) {
    const size_t orow = (bm + rbase + 8 * r) * (size_t)N + bn + cbase;
    if (!finalpass) {
      float4 o0, o1;
#pragma unroll
      for (int c = 0; c < 4; ++c) { (&o0.x)[c] = acc[r][c]; (&o1.x)[c] = acc[r][4 + c]; }
      *(float4*)&OUT[orow] = o0;
      *(float4*)&OUT[orow + 4] = o1;
    } else {
      const float4 p0 = *(const float4*)&OUT[orow];
      const float4 p1 = *(const float4*)&OUT[orow + 4];
      float4 o0, o1;
#pragma unroll
      for (int c = 0; c < 4; ++c) {
        const int col0 = bn + cbase + c;
        const int col1 = col0 + 4;
        const float v0 = fadd32(fadd32((&p0.x)[c], acc[r][c]), bias[col0]);
        const float v1 = fadd32(fadd32((&p1.x)[c], acc[r][4 + c]), bias[col1]);
        (&o0.x)[c] = th ? ((v0 >= th[col0]) ? v0 : 0.f) : v0;
        (&o1.x)[c] = th ? ((v1 >= th[col1]) ? v1 : 0.f) : v1;
      }
      *(float4*)&OUT[orow] = o0;
      *(float4*)&OUT[orow + 4] = o1;
    }
  }
#undef SQ_ISSUE
#undef SQ_XWRITE
#undef SQ_COMPUTE
}

// ---------------- residual + LN (float4; per-element ops frozen) ------------
__global__ __launch_bounds__(256) void k_add_ln(
    const float* __restrict__ A, const float* F,
    const float* __restrict__ g, const float* __restrict__ bet,
    float* O, int nrows) {
  __shared__ float zb[4][512];
  const int w = threadIdx.x >> 6;
  const int lane = threadIdx.x & 63;
  const int wid = blockIdx.x * 4 + w;
  if (wid >= nrows) return;
  const size_t row = (size_t)wid * 512;
  const int c0 = lane * 4, c1 = 256 + lane * 4;
  const float4 a0 = *(const float4*)&A[row + c0];
  const float4 a1 = *(const float4*)&A[row + c1];
  const float4 f0 = *(const float4*)&F[row + c0];
  const float4 f1 = *(const float4*)&F[row + c1];
  float4 z0, z1;
#pragma unroll
  for (int j = 0; j < 4; ++j) {
    (&z0.x)[j] = fadd32((&a0.x)[j], (&f0.x)[j]);
    (&z1.x)[j] = fadd32((&a1.x)[j], (&f1.x)[j]);
  }
  *(float4*)&zb[w][c0] = z0;
  *(float4*)&zb[w][c1] = z1;
  const float m = fmul32(np_pairwise512(zb[w], lane), 1.f / 512.f);
  float4 d0, d1, q0, q1;
#pragma unroll
  for (int j = 0; j < 4; ++j) {
    (&d0.x)[j] = fsub32((&z0.x)[j], m);
    (&d1.x)[j] = fsub32((&z1.x)[j], m);
    (&q0.x)[j] = fmul32((&d0.x)[j], (&d0.x)[j]);
    (&q1.x)[j] = fmul32((&d1.x)[j], (&d1.x)[j]);
  }
  *(float4*)&zb[w][c0] = q0;
  *(float4*)&zb[w][c1] = q1;
  const float var = fmul32(np_pairwise512(zb[w], lane), 1.f / 512.f);
  const float sdev = __fsqrt_rn(fadd32(var, 1e-5f));
  const float4 gg0 = *(const float4*)&g[c0], gg1 = *(const float4*)&g[c1];
  const float4 bb0 = *(const float4*)&bet[c0], bb1 = *(const float4*)&bet[c1];
  float4 o0, o1;
#pragma unroll
  for (int j = 0; j < 4; ++j) {
    (&o0.x)[j] = fadd32(fmul32(fdiv32((&d0.x)[j], sdev), (&gg0.x)[j]), (&bb0.x)[j]);
    (&o1.x)[j] = fadd32(fmul32(fdiv32((&d1.x)[j], sdev), (&gg1.x)[j]), (&bb1.x)[j]);
  }
  *(float4*)&O[row + c0] = o0;
  *(float4*)&O[row + c1] = o1;
}

// ---- fused residual + LN + pool4 (sub stage; sub never materialized) -------
__global__ __launch_bounds__(256) void k_add_ln_pool(
    const float* __restrict__ A, const float* __restrict__ F,
    const float* __restrict__ g, const float* __restrict__ bet,
    float* __restrict__ OUT) {
  __shared__ float zb[4][512];
  __shared__ float lnr[4][512];
  const int w = threadIdx.x >> 6;
  const int lane = threadIdx.x & 63;
  const int wid = blockIdx.x * 4 + w;
  const size_t row = (size_t)wid * 512;
  const int c0 = lane * 4, c1 = 256 + lane * 4;
  const float4 a0 = *(const float4*)&A[row + c0];
  const float4 a1 = *(const float4*)&A[row + c1];
  const float4 f0 = *(const float4*)&F[row + c0];
  const float4 f1 = *(const float4*)&F[row + c1];
  float4 z0, z1;
#pragma unroll
  for (int j = 0; j < 4; ++j) {
    (&z0.x)[j] = fadd32((&a0.x)[j], (&f0.x)[j]);
    (&z1.x)[j] = fadd32((&a1.x)[j], (&f1.x)[j]);
  }
  *(float4*)&zb[w][c0] = z0;
  *(float4*)&zb[w][c1] = z1;
  const float m = fmul32(np_pairwise512(zb[w], lane), 1.f / 512.f);
  float4 d0, d1, q0, q1;
#pragma unroll
  for (int j = 0; j < 4; ++j) {
    (&d0.x)[j] = fsub32((&z0.x)[j], m);
    (&d1.x)[j] = fsub32((&z1.x)[j], m);
    (&q0.x)[j] = fmul32((&d0.x)[j], (&d0.x)[j]);
    (&q1.x)[j] = fmul32((&d1.x)[j], (&d1.x)[j]);
  }
  *(float4*)&zb[w][c0] = q0;
  *(float4*)&zb[w][c1] = q1;
  const float var = fmul32(np_pairwise512(zb[w], lane), 1.f / 512.f);
  const float sdev = __fsqrt_rn(fadd32(var, 1e-5f));
  float4 o0, o1;
#pragma unroll
  for (int j = 0; j < 4; ++j) {
    (&o0.x)[j] = fadd32(fmul32(fdiv32((&d0.x)[j], sdev), g[c0 + j]), bet[c0 + j]);
    (&o1.x)[j] = fadd32(fmul32(fdiv32((&d1.x)[j], sdev), g[c1 + j]), bet[c1 + j]);
  }
  *(float4*)&lnr[w][c0] = o0;
  *(float4*)&lnr[w][c1] = o1;
  __syncthreads();
  if (threadIdx.x < 128) {
    const int c4 = threadIdx.x * 4;
    const float4 l0 = *(const float4*)&lnr[0][c4];
    const float4 l1 = *(const float4*)&lnr[1][c4];
    const float4 l2 = *(const float4*)&lnr[2][c4];
    const float4 l3 = *(const float4*)&lnr[3][c4];
    float4 o;
#pragma unroll
    for (int j = 0; j < 4; ++j) {
      const float s = fadd32(fadd32(fadd32((&l0.x)[j], (&l1.x)[j]), (&l2.x)[j]),
                             (&l3.x)[j]);
      (&o.x)[j] = fmul32(s, 0.25f);
    }
    *(float4*)&OUT[(size_t)blockIdx.x * 512 + c4] = o;
  }
}

// ---------------- transpose node weights: nwT[n][d][e] = nw[n][e][d] --------
__global__ __launch_bounds__(256) void k_transpose_nw(
    const float* __restrict__ nw, float* __restrict__ nwT) {
  const int idx = blockIdx.x * 256 + threadIdx.x;
  if (idx >= 15 * 4096) return;
  const int n = idx >> 12;
  const int e = (idx >> 6) & 63;
  const int d = idx & 63;
  nwT[(n << 12) + (d << 6) + e] = nw[idx];
}

// numpy einsum baseline-SSE model (bit-frozen).
#define NP_EINSUM64(inp, wp, out_)                                          \
  {                                                                         \
    float c0 = 0.f, c1 = 0.f, c2 = 0.f, c3 = 0.f;                           \
    _Pragma("unroll")                                                       \
    for (int q_ = 0; q_ < 4; ++q_) {                                        \
      const int b_ = 16 * q_;                                               \
      _Pragma("unroll")                                                     \
      for (int u_ = 3; u_ >= 0; --u_) {                                     \
        const int d0_ = b_ + 4 * u_;                                        \
        c0 = fadd32(fmul32(__shfl(inp, d0_ + 0), wp[(d0_ + 0) << 6]), c0);  \
        c1 = fadd32(fmul32(__shfl(inp, d0_ + 1), wp[(d0_ + 1) << 6]), c1);  \
        c2 = fadd32(fmul32(__shfl(inp, d0_ + 2), wp[(d0_ + 2) << 6]), c2);  \
        c3 = fadd32(fmul32(__shfl(inp, d0_ + 3), wp[(d0_ + 3) << 6]), c3);  \
      }                                                                     \
    }                                                                       \
    out_ = fadd32(fadd32(c0, c1), fadd32(c2, c3));                          \
  }

// ---------------- fused spiking tree (bit-frozen) ----------------
__global__ __launch_bounds__(256) void k_tree(
    const float* __restrict__ QKV, const float* __restrict__ nwT,
    const float* __restrict__ nb, const float* __restrict__ th,
    const float* __restrict__ tau, const float* __restrict__ vr,
    float* __restrict__ TK, float* __restrict__ TV) {
  __shared__ float st0[8][8][64];
  __shared__ float st1[4][8][64];
  __shared__ float st2[2][8][64];
  __shared__ float st3[8][64];
  __shared__ float outA[8][8][64];
  __shared__ float outB[4][8][64];
  const int tid = threadIdx.x, w = tid >> 6, lane = tid & 63;
  const int sq = blockIdx.x & 3, bh = blockIdx.x >> 2;
  const int b = bh >> 3, h = bh & 7;
  for (int pass = 0; pass < 2; ++pass) {
    const int koff = 512 + pass * 512;
    for (int r = w; r < 64; r += 4) {
      const int n = r >> 3, sl = r & 7, sg = sq * 8 + sl;
      const float inp = QKV[((size_t)(b * 512 + n * 32 + sg)) * 1536 + koff + h * 64 + lane];
      const int node = 7 + n, pc = node * 64 + lane;
      const float* wp = nwT + node * 4096 + lane;
      float tot;
      NP_EINSUM64(inp, wp, tot);
      const float proj = fadd32(tot, nb[pc]);
      const float v = pass ? fadd32(fmul32(tau[pc], st0[n][sl][lane]), proj) : proj;
      const bool sp = v >= th[pc];
      if (!pass) st0[n][sl][lane] = sp ? vr[pc] : v;
      outA[n][sl][lane] = sp ? proj : 0.f;
    }
    __syncthreads();
    for (int r = w; r < 32; r += 4) {
      const int n = r >> 3, sl = r & 7;
      const float inp = fmul32(0.5f, fadd32(outA[2 * n][sl][lane], outA[2 * n + 1][sl][lane]));
      const int node = 3 + n, pc = node * 64 + lane;
      const float* wp = nwT + node * 4096 + lane;
      float tot;
      NP_EINSUM64(inp, wp, tot);
      const float proj = fadd32(tot, nb[pc]);
      const float v = pass ? fadd32(fmul32(tau[pc], st1[n][sl][lane]), proj) : proj;
      const bool sp = v >= th[pc];
      if (!pass) st1[n][sl][lane] = sp ? vr[pc] : v;
      outB[n][sl][lane] = sp ? proj : 0.f;
    }
    __syncthreads();
    for (int r = w; r < 16; r += 4) {
      const int n = r >> 3, sl = r & 7;
      const float inp = fmul32(0.5f, fadd32(outB[2 * n][sl][lane], outB[2 * n + 1][sl][lane]));
      const int node = 1 + n, pc = node * 64 + lane;
      const float* wp = nwT + node * 4096 + lane;
      float tot;
      NP_EINSUM64(inp, wp, tot);
      const float proj = fadd32(tot, nb[pc]);
      const float v = pass ? fadd32(fmul32(tau[pc], st2[n][sl][lane]), proj) : proj;
      const bool sp = v >= th[pc];
      if (!pass) st2[n][sl][lane] = sp ? vr[pc] : v;
      outA[n][sl][lane] = sp ? proj : 0.f;
    }
    __syncthreads();
    for (int r = w; r < 8; r += 4) {
      const int sl = r & 7, sg = sq * 8 + sl;
      const float inp = fmul32(0.5f, fadd32(outA[0][sl][lane], outA[1][sl][lane]));
      const int pc = lane;
      const float* wp = nwT + lane;
      float tot;
      NP_EINSUM64(inp, wp, tot);
      const float proj = fadd32(tot, nb[pc]);
      const float v = pass ? fadd32(fmul32(tau[pc], st3[sl][lane]), proj) : proj;
      const bool sp = v >= th[pc];
      if (!pass) st3[sl][lane] = sp ? vr[pc] : v;
      float* dst = pass ? TV : TK;
      dst[((size_t)bh * 32 + sg) * 64 + lane] = sp ? proj : 0.f;
    }
    __syncthreads();
  }
}

// ---------------- attention (post-gate, relaxed; fp32 chains) ----------------
__global__ __launch_bounds__(256) void k_attn(
    const float* __restrict__ qkv, const float* __restrict__ treeK,
    const float* __restrict__ treeV, float* __restrict__ attn) {
  __shared__ float Ks[32][65];
  __shared__ float Vs[32][64];
  __shared__ float qs[4][64];
  const int tid = threadIdx.x;
  const int bh = blockIdx.x >> 7;
  const int lq0 = (blockIdx.x & 127) * 4;
  const int b = bh >> 3, h = bh & 7;
  for (int i = tid; i < 2048; i += 256) {
    const int j = i >> 6, d = i & 63;
    Ks[j][d] = treeK[((size_t)bh * 32 + j) * 64 + d];
    Vs[j][d] = treeV[((size_t)bh * 32 + j) * 64 + d];
  }
  {
    const int w = tid >> 6, d = tid & 63;
    qs[w][d] = qkv[((size_t)(b * 512) + lq0 + w) * 1536 + h * 64 + d];
  }
  __syncthreads();
  const int w = tid >> 6;
  const int lane = tid & 63;
  const int j = lane & 31;
  float sc = 0.f;
#pragma unroll
  for (int d = 0; d < 64; ++d) sc = __fmaf_rn(qs[w][d], Ks[j][d], sc);
  sc = fmul32(sc, 0.125f);
  float m = sc;
#pragma unroll
  for (int k = 1; k < 32; k <<= 1) m = fmaxf(m, __shfl_xor(m, k));
  float p = expf(fsub32(sc, m));
  float sum = p;
#pragma unroll
  for (int k = 1; k < 32; k <<= 1) sum += __shfl_xor(sum, k);
  p = fdiv32(p, sum);
  float acc = 0.f;
#pragma unroll
  for (int jj = 0; jj < 32; ++jj)
    acc = __fmaf_rn(__shfl(p, jj), Vs[jj][lane], acc);
  attn[((size_t)(b * 512) + lq0 + w) * 512 + h * 64 + lane] = acc;
}

// ---------------- linear interpolation 512 -> 4096 rows ----------------
__global__ __launch_bounds__(256) void k_interp(
    const float* __restrict__ rows, float* __restrict__ out) {
  const int wid = blockIdx.x * 4 + (threadIdx.x >> 6);  // b*4096+s
  const int lane = threadIdx.x & 63;
  const int b = wid >> 12;
  const int s = wid & 4095;
  const double src = fmax(((double)s + 0.5) * 0.125 - 0.5, 0.0);
  const int i0 = (int)src;
  const int i1 = min(i0 + 1, 511);
  const double w1 = src - (double)i0;
  const double w0 = 1.0 - w1;
  const size_t r0 = ((size_t)b * 512 + i0) * 512;
  const size_t r1 = ((size_t)b * 512 + i1) * 512;
  const size_t o = (size_t)wid * 512;
#pragma unroll
  for (int k = 0; k < 2; ++k) {
    const int c4 = lane + 64 * k;
    const float4 a = *reinterpret_cast<const float4*>(&rows[r0 + (size_t)c4 * 4]);
    const float4 c = *reinterpret_cast<const float4*>(&rows[r1 + (size_t)c4 * 4]);
    float4 r;
    r.x = (float)((double)a.x * w0 + (double)c.x * w1);
    r.y = (float)((double)a.y * w0 + (double)c.y * w1);
    r.z = (float)((double)a.z * w0 + (double)c.z * w1);
    r.w = (float)((double)a.w * w0 + (double)c.w * w1);
    *reinterpret_cast<float4*>(&out[o + (size_t)c4 * 4]) = r;
  }
}

extern "C" void kernel_launch(void* const* d_in, const int* in_sizes, int n_in,
                              void* d_out, int out_size, void* d_ws, size_t ws_size,
                              hipStream_t stream) {
  const int*   text    = (const int*)d_in[0];
  const float* pe      = (const float*)d_in[1];
  const float* id_w    = (const float*)d_in[2];
  const float* id_b    = (const float*)d_in[3];
  const float* eg      = (const float*)d_in[4];
  const float* ebeta   = (const float*)d_in[5];
  const float* sub_w   = (const float*)d_in[6];
  const float* sub_b   = (const float*)d_in[7];
  const float* sub_th  = (const float*)d_in[8];
  const float* sub_ng  = (const float*)d_in[11];
  const float* sub_nb  = (const float*)d_in[12];
  const float* word_w  = (const float*)d_in[13];
  const float* word_b  = (const float*)d_in[14];
  const float* word_th = (const float*)d_in[15];
  const float* word_ng = (const float*)d_in[18];
  const float* word_nb = (const float*)d_in[19];
  const float* qkv_w   = (const float*)d_in[20];
  const float* qkv_b   = (const float*)d_in[21];
  const float* node_w  = (const float*)d_in[22];
  const float* node_b  = (const float*)d_in[23];
  const float* node_th = (const float*)d_in[24];
  const float* node_tau= (const float*)d_in[25];
  const float* node_vr = (const float*)d_in[26];
  const float* out_ng  = (const float*)d_in[27];
  const float* out_nb  = (const float*)d_in[28];

  float* O   = (float*)d_out;   // 67,108,864 floats
  float* WSF = (float*)d_ws;

  // d_out regions (floats)
  float* FU  = O;               // fused1 [0 : 33554432)
  float* GZ1 = O + 33554432;    // sub P1 -> gated proj [33554432 : 67108864)
  float* WD  = O + 33554432;    // word [33554432 : 41943040)
  float* GZ2 = O + 41943040;    // word P1 -> gated proj (dead before qkv write)
  float* QKV = O + 41943040;    // qkv P1 -> qkv [41943040 : 67108864)

  // ws regions (floats)
  float* W1   = WSF;            // [0 : 8388608)
  float* NWT  = WSF + 8388608;  // 61440
  float* TK   = WSF + 8450048;  // 524288
  float* TV   = WSF + 8974336;  // 524288
  float* ROWS = WSF + 9498624;  // 8388608
  float* WTs  = WSF + 17887232; // 262144  (sub_w^T  [512][512])
  float* WTw  = WSF + 18149376; // 262144  (word_w^T [512][512])
  float* WTq  = WSF + 18411520; // 786432  (qkv_w^T  [512][1536])
  float* ATT  = WSF;            // reuses W1 (dead after word LN)

  // 0. weight transposes (independent of activations)
  k_transpose_w<<<dim3(16, 16), 256, 0, stream>>>(sub_w, WTs, 512);
  k_transpose_w<<<dim3(16, 16), 256, 0, stream>>>(word_w, WTw, 512);
  k_transpose_w<<<dim3(48, 16), 256, 0, stream>>>(qkv_w, WTq, 1536);
  k_transpose_nw<<<240, 256, 0, stream>>>(node_w, NWT);
  // 1. embed + LN + pool2 -> FU
  k_embed<<<16384, 256, 0, stream>>>(text, pe, id_w, id_b, eg, ebeta, FU);
  // 2. GZ1 = gate(FU @ sub_w^T + b)  — split panels A(12 tiles) + B(4 tiles)
  k_gemm_sq<<<dim3(512, 2), 512, 0, stream>>>(FU, WTs, sub_b, sub_th, GZ1, 512, 0, 12, 0);
  k_gemm_sq<<<dim3(512, 2), 512, 0, stream>>>(FU, WTs, sub_b, sub_th, GZ1, 512, 384, 4, 1);
  // 3. W1 = pool4(LN(GZ1 + FU))  — sub never materialized
  k_add_ln_pool<<<16384, 256, 0, stream>>>(GZ1, FU, sub_ng, sub_nb, W1);
  // 4. GZ2 = gate(W1 @ word_w^T + b)
  k_gemm_sq<<<dim3(128, 2), 512, 0, stream>>>(W1, WTw, word_b, word_th, GZ2, 512, 0, 12, 0);
  k_gemm_sq<<<dim3(128, 2), 512, 0, stream>>>(W1, WTw, word_b, word_th, GZ2, 512, 384, 4, 1);
  // 5. word = LN(GZ2 + W1) -> WD
  k_add_ln<<<4096, 256, 0, stream>>>(GZ2, W1, word_ng, word_nb, WD, 16384);
  // 6. QKV = WD @ qkv_w^T + b
  k_gemm_sq<<<dim3(128, 6), 512, 0, stream>>>(WD, WTq, qkv_b, nullptr, QKV, 1536, 0, 12, 0);
  k_gemm_sq<<<dim3(128, 6), 512, 0, stream>>>(WD, WTq, qkv_b, nullptr, QKV, 1536, 384, 4, 1);
  // 7. fused spiking tree -> TK, TV
  k_tree<<<1024, 256, 0, stream>>>(QKV, NWT, node_b, node_th,
                                   node_tau, node_vr, TK, TV);
  // 8. attention -> ATT (reuses dead W1 space)
  k_attn<<<32768, 256, 0, stream>>>(QKV, TK, TV, ATT);
  // 9. rows = LN(ATT + word) -> ROWS
  k_add_ln<<<4096, 256, 0, stream>>>(ATT, WD, out_ng, out_nb, ROWS, 16384);
  // 10. interpolate 512 -> 4096 rows, full fp32 d_out overwrite
  k_interp<<<32768, 256, 0, stream>>>(ROWS, O);
}

// Round 16
// 1866.075 us; speedup vs baseline: 5.2605x; 5.2605x over previous
//
#include <hip/hip_runtime.h>
#include <math.h>

// ---------------------------------------------------------------------------
// TreeTextEmbed — numpy-faithful fp32 pipeline, round 16 (REVERT to r13 best).
// NUMERICS FROZEN (r7-r15 passed, absmax 0.015625): ascending-k fp32 FMA chain
// w/ 384/128 panels; AVX512 pairwise mean; baseline-SSE einsum; __f*_rn
// elementwise in np op order.
// r15 post-mortem: 8x8-acc split-K spilled (WRITE 9.3GB, VALU 5%) -> revert
// to the proven r12/r13 GEMM: BM=64/BN=256/BK=32, 512thr, 4x8 per-thread,
// gload_lds double-buffer, counted-vmcnt raw barriers. 1869us baseline.
// ---------------------------------------------------------------------------

__device__ __forceinline__ float fadd32(float a, float b) { return __fadd_rn(a, b); }
__device__ __forceinline__ float fmul32(float a, float b) { return __fmul_rn(a, b); }
__device__ __forceinline__ float fsub32(float a, float b) { return __fsub_rn(a, b); }
__device__ __forceinline__ float fdiv32(float a, float b) { return __fdiv_rn(a, b); }

// async global->LDS, 16B per lane; LDS dest = wave-uniform base + lane*16
__device__ __forceinline__ void gload16(const float* g, float* l) {
  __builtin_amdgcn_global_load_lds(
      (const __attribute__((address_space(1))) void*)g,
      (__attribute__((address_space(3))) void*)l, 16, 0, 0);
}

// numpy pairwise sum of contiguous 512 floats, AVX512 model (bit-frozen).
__device__ __forceinline__ float np_pairwise512(const float* row, int lane) {
  const int L = lane >> 4, j = lane & 15;
  const float* p = row + 128 * L + j;
  const float r0 = p[0],  r1 = p[16], r2 = p[32],  r3 = p[48];
  const float r4 = p[64], r5 = p[80], r6 = p[96],  r7 = p[112];
  float v = fadd32(fadd32(fadd32(r0, r1), fadd32(r2, r3)),
                   fadd32(fadd32(r4, r5), fadd32(r6, r7)));
  v = fadd32(v, __shfl_xor(v, 8));
  v = fadd32(v, __shfl_xor(v, 4));
  v = fadd32(v, __shfl_xor(v, 2));
  v = fadd32(v, __shfl_xor(v, 1));
  v = fadd32(v, __shfl_xor(v, 16));
  v = fadd32(v, __shfl_xor(v, 32));
  return v;
}

// ---------------- K1: embed + LN + pool2 (float4; per-element ops frozen) ----
__global__ __launch_bounds__(256) void k_embed(
    const int* __restrict__ text, const float* __restrict__ pe,
    const float* __restrict__ id_w, const float* __restrict__ id_b,
    const float* __restrict__ eg, const float* __restrict__ eb,
    float* __restrict__ fused) {
  __shared__ float rb[4][512];
  const int w = threadIdx.x >> 6;
  const int lane = threadIdx.x & 63;
  const int wid = blockIdx.x * 4 + w;  // row b*2048+t
  const int b = wid >> 11;
  const int t = wid & 2047;
  const int c0 = lane * 4, c1 = 256 + lane * 4;
  const float4 iw0 = *(const float4*)&id_w[c0], iw1 = *(const float4*)&id_w[c1];
  const float4 ib0 = *(const float4*)&id_b[c0], ib1 = *(const float4*)&id_b[c1];
  const float4 g0  = *(const float4*)&eg[c0],  g1  = *(const float4*)&eg[c1];
  const float4 e0  = *(const float4*)&eb[c0],  e1  = *(const float4*)&eb[c1];
  float4 fus0, fus1;
#pragma unroll
  for (int ss = 0; ss < 2; ++ss) {
    const int s = 2 * t + ss;
    const float idv = (float)text[b * 4096 + s];
    const float4 p0 = *(const float4*)&pe[(size_t)s * 512 + c0];
    const float4 p1 = *(const float4*)&pe[(size_t)s * 512 + c1];
    float4 x0, x1;
#pragma unroll
    for (int j = 0; j < 4; ++j) {
      (&x0.x)[j] = fadd32(fadd32(fmul32(idv, (&iw0.x)[j]), (&ib0.x)[j]), (&p0.x)[j]);
      (&x1.x)[j] = fadd32(fadd32(fmul32(idv, (&iw1.x)[j]), (&ib1.x)[j]), (&p1.x)[j]);
    }
    *(float4*)&rb[w][c0] = x0;
    *(float4*)&rb[w][c1] = x1;
    const float m = fmul32(np_pairwise512(rb[w], lane), 1.f / 512.f);
    float4 d0, d1, q0, q1;
#pragma unroll
    for (int j = 0; j < 4; ++j) {
      (&d0.x)[j] = fsub32((&x0.x)[j], m);
      (&d1.x)[j] = fsub32((&x1.x)[j], m);
      (&q0.x)[j] = fmul32((&d0.x)[j], (&d0.x)[j]);
      (&q1.x)[j] = fmul32((&d1.x)[j], (&d1.x)[j]);
    }
    *(float4*)&rb[w][c0] = q0;
    *(float4*)&rb[w][c1] = q1;
    const float var = fmul32(np_pairwise512(rb[w], lane), 1.f / 512.f);
    const float sdev = __fsqrt_rn(fadd32(var, 1e-5f));
#pragma unroll
    for (int j = 0; j < 4; ++j) {
      const float l0 = fadd32(fmul32(fdiv32((&d0.x)[j], sdev), (&g0.x)[j]), (&e0.x)[j]);
      const float l1 = fadd32(fmul32(fdiv32((&d1.x)[j], sdev), (&g1.x)[j]), (&e1.x)[j]);
      if (ss) {
        (&fus0.x)[j] = fmul32(fadd32((&fus0.x)[j], l0), 0.5f);
        (&fus1.x)[j] = fmul32(fadd32((&fus1.x)[j], l1), 0.5f);
      } else {
        (&fus0.x)[j] = l0;
        (&fus1.x)[j] = l1;
      }
    }
  }
  const size_t row = (size_t)wid * 512;
  *(float4*)&fused[row + c0] = fus0;
  *(float4*)&fused[row + c1] = fus1;
}

// ---------------- tiled weight transpose: WT[k][n] = W[n][k], K=512 ----------
__global__ __launch_bounds__(256) void k_transpose_w(
    const float* __restrict__ W, float* __restrict__ WT, int Nn) {
  __shared__ float t[32][33];
  const int n0 = blockIdx.x * 32, k0 = blockIdx.y * 32;
  const int li = threadIdx.x & 31, wi = threadIdx.x >> 5;
  for (int r = wi; r < 32; r += 8)
    t[r][li] = W[(size_t)(n0 + r) * 512 + k0 + li];
  __syncthreads();
  for (int r = wi; r < 32; r += 8)
    WT[(size_t)(k0 + r) * Nn + n0 + li] = t[li][r];
}

// ---- unified np-sgemm from WT[K][N]: OUT = [gate](X @ W^T + bias)
// BM=64, BN=256, BK=32; 512 thr (8 waves); per-thread 4 rows x 8 cols.
// Counted-vmcnt double-buffer: STAGE issues 5 gload_lds per wave;
// vmcnt(5) waits tile t while t+1 stays in flight. Raw s_barriers.
// Chain per element: k ascending, panels [0,384)+[384,512)  (bit-frozen).
#define GEMM_INNER(acc, buf)                                         \
  _Pragma("unroll")                                                  \
  for (int kq = 0; kq < 32; kq += 4) {                               \
    float4 xf[4];                                                    \
    _Pragma("unroll")                                                \
    for (int r = 0; r < 4; ++r)                                      \
      xf[r] = *(const float4*)&Xs[buf][rg * 4 + r][kq];              \
    _Pragma("unroll")                                                \
    for (int u = 0; u < 4; ++u) {                                    \
      const float4 w0 = *(const float4*)&Ws[buf][kq + u][cg * 4];    \
      const float4 w1 = *(const float4*)&Ws[buf][kq + u][128 + cg * 4]; \
      _Pragma("unroll")                                              \
      for (int r = 0; r < 4; ++r) {                                  \
        const float xv = (&xf[r].x)[u];                              \
        acc[r][0] = __fmaf_rn(xv, w0.x, acc[r][0]);                  \
        acc[r][1] = __fmaf_rn(xv, w0.y, acc[r][1]);                  \
        acc[r][2] = __fmaf_rn(xv, w0.z, acc[r][2]);                  \
        acc[r][3] = __fmaf_rn(xv, w0.w, acc[r][3]);                  \
        acc[r][4] = __fmaf_rn(xv, w1.x, acc[r][4]);                  \
        acc[r][5] = __fmaf_rn(xv, w1.y, acc[r][5]);                  \
        acc[r][6] = __fmaf_rn(xv, w1.z, acc[r][6]);                  \
        acc[r][7] = __fmaf_rn(xv, w1.w, acc[r][7]);                  \
      }                                                              \
    }                                                                \
  }

// stage one 64x32 X tile + 32x256 W tile into buf (8 waves, 5 gloads each)
#define STAGE(buf, k0)                                                        \
  {                                                                           \
    gload16(&X[(bm + wvid * 8 + (lane >> 3)) * 512 + (k0) + (lane & 7) * 4],  \
            &Xs[buf][wvid * 8][0]);                                           \
    _Pragma("unroll")                                                         \
    for (int c = 0; c < 4; ++c)                                               \
      gload16(&WT[(size_t)((k0) + wvid * 4 + c) * N + bn + lane * 4],         \
              &Ws[buf][wvid * 4 + c][0]);                                     \
  }

__global__ __launch_bounds__(512) void k_gemm_nt(
    const float* __restrict__ X, const float* __restrict__ WT,
    const float* __restrict__ bias, const float* __restrict__ th,
    float* __restrict__ OUT, int N) {
  __shared__ float Xs[2][64][32];    // 16 KB — linear for gload_lds
  __shared__ float Ws[2][32][256];   // 64 KB — linear for gload_lds
  const int tid = threadIdx.x;
  const int wvid = tid >> 6, lane = tid & 63;
  const int rg = tid >> 5;   // 0..15 (row group, 4 rows each)
  const int cg = tid & 31;   // 0..31 (col group, 2x4 cols each)
  const size_t bm = (size_t)blockIdx.x * 64;
  const int bn = blockIdx.y * 256;

  float accA[4][8], accB[4][8];
#pragma unroll
  for (int r = 0; r < 4; ++r)
#pragma unroll
    for (int c = 0; c < 8; ++c) { accA[r][c] = 0.f; accB[r][c] = 0.f; }

  STAGE(0, 0);
  asm volatile("s_waitcnt vmcnt(0)" ::: "memory");
  asm volatile("s_barrier" ::: "memory");
  for (int t = 0; t < 16; ++t) {
    const int cur = t & 1;
    if (t < 15) {
      STAGE(cur ^ 1, (t + 1) * 32);                     // +5 loads (tile t+1)
      asm volatile("s_waitcnt vmcnt(5)" ::: "memory");  // tile t done, t+1 in flight
    } else {
      asm volatile("s_waitcnt vmcnt(0)" ::: "memory");
    }
    asm volatile("s_barrier" ::: "memory");             // tile t visible to all
    if (t < 12) { GEMM_INNER(accA, cur); } else { GEMM_INNER(accB, cur); }
    asm volatile("s_barrier" ::: "memory");             // reads done before overwrite
  }
  // epilogue: C = P1+P2; +bias; optional gate (bit-frozen sequence)
#pragma unroll
  for (int r = 0; r < 4; ++r) {
    const size_t rb = (bm + rg * 4 + r) * (size_t)N;
    float4 o0, o1;
#pragma unroll
    for (int c = 0; c < 4; ++c) {
      const int col0 = bn + cg * 4 + c;
      const int col1 = bn + 128 + cg * 4 + c;
      const float v0 = fadd32(fadd32(accA[r][c], accB[r][c]), bias[col0]);
      const float v1 = fadd32(fadd32(accA[r][4 + c], accB[r][4 + c]), bias[col1]);
      (&o0.x)[c] = th ? ((v0 >= th[col0]) ? v0 : 0.f) : v0;
      (&o1.x)[c] = th ? ((v1 >= th[col1]) ? v1 : 0.f) : v1;
    }
    *(float4*)&OUT[rb + bn + cg * 4] = o0;
    *(float4*)&OUT[rb + bn + 128 + cg * 4] = o1;
  }
}

// ---------------- residual + LN (float4; per-element ops frozen) ------------
__global__ __launch_bounds__(256) void k_add_ln(
    const float* __restrict__ A, const float* F,
    const float* __restrict__ g, const float* __restrict__ bet,
    float* O, int nrows) {
  __shared__ float zb[4][512];
  const int w = threadIdx.x >> 6;
  const int lane = threadIdx.x & 63;
  const int wid = blockIdx.x * 4 + w;
  if (wid >= nrows) return;
  const size_t row = (size_t)wid * 512;
  const int c0 = lane * 4, c1 = 256 + lane * 4;
  const float4 a0 = *(const float4*)&A[row + c0];
  const float4 a1 = *(const float4*)&A[row + c1];
  const float4 f0 = *(const float4*)&F[row + c0];
  const float4 f1 = *(const float4*)&F[row + c1];
  float4 z0, z1;
#pragma unroll
  for (int j = 0; j < 4; ++j) {
    (&z0.x)[j] = fadd32((&a0.x)[j], (&f0.x)[j]);
    (&z1.x)[j] = fadd32((&a1.x)[j], (&f1.x)[j]);
  }
  *(float4*)&zb[w][c0] = z0;
  *(float4*)&zb[w][c1] = z1;
  const float m = fmul32(np_pairwise512(zb[w], lane), 1.f / 512.f);
  float4 d0, d1, q0, q1;
#pragma unroll
  for (int j = 0; j < 4; ++j) {
    (&d0.x)[j] = fsub32((&z0.x)[j], m);
    (&d1.x)[j] = fsub32((&z1.x)[j], m);
    (&q0.x)[j] = fmul32((&d0.x)[j], (&d0.x)[j]);
    (&q1.x)[j] = fmul32((&d1.x)[j], (&d1.x)[j]);
  }
  *(float4*)&zb[w][c0] = q0;
  *(float4*)&zb[w][c1] = q1;
  const float var = fmul32(np_pairwise512(zb[w], lane), 1.f / 512.f);
  const float sdev = __fsqrt_rn(fadd32(var, 1e-5f));
  const float4 gg0 = *(const float4*)&g[c0], gg1 = *(const float4*)&g[c1];
  const float4 bb0 = *(const float4*)&bet[c0], bb1 = *(const float4*)&bet[c1];
  float4 o0, o1;
#pragma unroll
  for (int j = 0; j < 4; ++j) {
    (&o0.x)[j] = fadd32(fmul32(fdiv32((&d0.x)[j], sdev), (&gg0.x)[j]), (&bb0.x)[j]);
    (&o1.x)[j] = fadd32(fmul32(fdiv32((&d1.x)[j], sdev), (&gg1.x)[j]), (&bb1.x)[j]);
  }
  *(float4*)&O[row + c0] = o0;
  *(float4*)&O[row + c1] = o1;
}

// ---- fused residual + LN + pool4 (sub stage; sub never materialized) -------
__global__ __launch_bounds__(256) void k_add_ln_pool(
    const float* __restrict__ A, const float* __restrict__ F,
    const float* __restrict__ g, const float* __restrict__ bet,
    float* __restrict__ OUT) {
  __shared__ float zb[4][512];
  __shared__ float lnr[4][512];
  const int w = threadIdx.x >> 6;
  const int lane = threadIdx.x & 63;
  const int wid = blockIdx.x * 4 + w;
  const size_t row = (size_t)wid * 512;
  const int c0 = lane * 4, c1 = 256 + lane * 4;
  const float4 a0 = *(const float4*)&A[row + c0];
  const float4 a1 = *(const float4*)&A[row + c1];
  const float4 f0 = *(const float4*)&F[row + c0];
  const float4 f1 = *(const float4*)&F[row + c1];
  float4 z0, z1;
#pragma unroll
  for (int j = 0; j < 4; ++j) {
    (&z0.x)[j] = fadd32((&a0.x)[j], (&f0.x)[j]);
    (&z1.x)[j] = fadd32((&a1.x)[j], (&f1.x)[j]);
  }
  *(float4*)&zb[w][c0] = z0;
  *(float4*)&zb[w][c1] = z1;
  const float m = fmul32(np_pairwise512(zb[w], lane), 1.f / 512.f);
  float4 d0, d1, q0, q1;
#pragma unroll
  for (int j = 0; j < 4; ++j) {
    (&d0.x)[j] = fsub32((&z0.x)[j], m);
    (&d1.x)[j] = fsub32((&z1.x)[j], m);
    (&q0.x)[j] = fmul32((&d0.x)[j], (&d0.x)[j]);
    (&q1.x)[j] = fmul32((&d1.x)[j], (&d1.x)[j]);
  }
  *(float4*)&zb[w][c0] = q0;
  *(float4*)&zb[w][c1] = q1;
  const float var = fmul32(np_pairwise512(zb[w], lane), 1.f / 512.f);
  const float sdev = __fsqrt_rn(fadd32(var, 1e-5f));
  float4 o0, o1;
#pragma unroll
  for (int j = 0; j < 4; ++j) {
    (&o0.x)[j] = fadd32(fmul32(fdiv32((&d0.x)[j], sdev), g[c0 + j]), bet[c0 + j]);
    (&o1.x)[j] = fadd32(fmul32(fdiv32((&d1.x)[j], sdev), g[c1 + j]), bet[c1 + j]);
  }
  *(float4*)&lnr[w][c0] = o0;
  *(float4*)&lnr[w][c1] = o1;
  __syncthreads();
  if (threadIdx.x < 128) {
    const int c4 = threadIdx.x * 4;
    const float4 l0 = *(const float4*)&lnr[0][c4];
    const float4 l1 = *(const float4*)&lnr[1][c4];
    const float4 l2 = *(const float4*)&lnr[2][c4];
    const float4 l3 = *(const float4*)&lnr[3][c4];
    float4 o;
#pragma unroll
    for (int j = 0; j < 4; ++j) {
      const float s = fadd32(fadd32(fadd32((&l0.x)[j], (&l1.x)[j]), (&l2.x)[j]),
                             (&l3.x)[j]);
      (&o.x)[j] = fmul32(s, 0.25f);
    }
    *(float4*)&OUT[(size_t)blockIdx.x * 512 + c4] = o;
  }
}

// ---------------- transpose node weights: nwT[n][d][e] = nw[n][e][d] --------
__global__ __launch_bounds__(256) void k_transpose_nw(
    const float* __restrict__ nw, float* __restrict__ nwT) {
  const int idx = blockIdx.x * 256 + threadIdx.x;
  if (idx >= 15 * 4096) return;
  const int n = idx >> 12;
  const int e = (idx >> 6) & 63;
  const int d = idx & 63;
  nwT[(n << 12) + (d << 6) + e] = nw[idx];
}

// numpy einsum baseline-SSE model (bit-frozen).
#define NP_EINSUM64(inp, wp, out_)                                          \
  {                                                                         \
    float c0 = 0.f, c1 = 0.f, c2 = 0.f, c3 = 0.f;                           \
    _Pragma("unroll")                                                       \
    for (int q_ = 0; q_ < 4; ++q_) {                                        \
      const int b_ = 16 * q_;                                               \
      _Pragma("unroll")                                                     \
      for (int u_ = 3; u_ >= 0; --u_) {                                     \
        const int d0_ = b_ + 4 * u_;                                        \
        c0 = fadd32(fmul32(__shfl(inp, d0_ + 0), wp[(d0_ + 0) << 6]), c0);  \
        c1 = fadd32(fmul32(__shfl(inp, d0_ + 1), wp[(d0_ + 1) << 6]), c1);  \
        c2 = fadd32(fmul32(__shfl(inp, d0_ + 2), wp[(d0_ + 2) << 6]), c2);  \
        c3 = fadd32(fmul32(__shfl(inp, d0_ + 3), wp[(d0_ + 3) << 6]), c3);  \
      }                                                                     \
    }                                                                       \
    out_ = fadd32(fadd32(c0, c1), fadd32(c2, c3));                          \
  }

// ---------------- fused spiking tree (bit-frozen) ----------------
__global__ __launch_bounds__(256) void k_tree(
    const float* __restrict__ QKV, const float* __restrict__ nwT,
    const float* __restrict__ nb, const float* __restrict__ th,
    const float* __restrict__ tau, const float* __restrict__ vr,
    float* __restrict__ TK, float* __restrict__ TV) {
  __shared__ float st0[8][8][64];
  __shared__ float st1[4][8][64];
  __shared__ float st2[2][8][64];
  __shared__ float st3[8][64];
  __shared__ float outA[8][8][64];
  __shared__ float outB[4][8][64];
  const int tid = threadIdx.x, w = tid >> 6, lane = tid & 63;
  const int sq = blockIdx.x & 3, bh = blockIdx.x >> 2;
  const int b = bh >> 3, h = bh & 7;
  for (int pass = 0; pass < 2; ++pass) {
    const int koff = 512 + pass * 512;
    for (int r = w; r < 64; r += 4) {
      const int n = r >> 3, sl = r & 7, sg = sq * 8 + sl;
      const float inp = QKV[((size_t)(b * 512 + n * 32 + sg)) * 1536 + koff + h * 64 + lane];
      const int node = 7 + n, pc = node * 64 + lane;
      const float* wp = nwT + node * 4096 + lane;
      float tot;
      NP_EINSUM64(inp, wp, tot);
      const float proj = fadd32(tot, nb[pc]);
      const float v = pass ? fadd32(fmul32(tau[pc], st0[n][sl][lane]), proj) : proj;
      const bool sp = v >= th[pc];
      if (!pass) st0[n][sl][lane] = sp ? vr[pc] : v;
      outA[n][sl][lane] = sp ? proj : 0.f;
    }
    __syncthreads();
    for (int r = w; r < 32; r += 4) {
      const int n = r >> 3, sl = r & 7;
      const float inp = fmul32(0.5f, fadd32(outA[2 * n][sl][lane], outA[2 * n + 1][sl][lane]));
      const int node = 3 + n, pc = node * 64 + lane;
      const float* wp = nwT + node * 4096 + lane;
      float tot;
      NP_EINSUM64(inp, wp, tot);
      const float proj = fadd32(tot, nb[pc]);
      const float v = pass ? fadd32(fmul32(tau[pc], st1[n][sl][lane]), proj) : proj;
      const bool sp = v >= th[pc];
      if (!pass) st1[n][sl][lane] = sp ? vr[pc] : v;
      outB[n][sl][lane] = sp ? proj : 0.f;
    }
    __syncthreads();
    for (int r = w; r < 16; r += 4) {
      const int n = r >> 3, sl = r & 7;
      const float inp = fmul32(0.5f, fadd32(outB[2 * n][sl][lane], outB[2 * n + 1][sl][lane]));
      const int node = 1 + n, pc = node * 64 + lane;
      const float* wp = nwT + node * 4096 + lane;
      float tot;
      NP_EINSUM64(inp, wp, tot);
      const float proj = fadd32(tot, nb[pc]);
      const float v = pass ? fadd32(fmul32(tau[pc], st2[n][sl][lane]), proj) : proj;
      const bool sp = v >= th[pc];
      if (!pass) st2[n][sl][lane] = sp ? vr[pc] : v;
      outA[n][sl][lane] = sp ? proj : 0.f;
    }
    __syncthreads();
    for (int r = w; r < 8; r += 4) {
      const int sl = r & 7, sg = sq * 8 + sl;
      const float inp = fmul32(0.5f, fadd32(outA[0][sl][lane], outA[1][sl][lane]));
      const int pc = lane;
      const float* wp = nwT + lane;
      float tot;
      NP_EINSUM64(inp, wp, tot);
      const float proj = fadd32(tot, nb[pc]);
      const float v = pass ? fadd32(fmul32(tau[pc], st3[sl][lane]), proj) : proj;
      const bool sp = v >= th[pc];
      if (!pass) st3[sl][lane] = sp ? vr[pc] : v;
      float* dst = pass ? TV : TK;
      dst[((size_t)bh * 32 + sg) * 64 + lane] = sp ? proj : 0.f;
    }
    __syncthreads();
  }
}

// ---------------- attention (post-gate, relaxed; fp32 chains) ----------------
__global__ __launch_bounds__(256) void k_attn(
    const float* __restrict__ qkv, const float* __restrict__ treeK,
    const float* __restrict__ treeV, float* __restrict__ attn) {
  __shared__ float Ks[32][65];
  __shared__ float Vs[32][64];
  __shared__ float qs[4][64];
  const int tid = threadIdx.x;
  const int bh = blockIdx.x >> 7;
  const int lq0 = (blockIdx.x & 127) * 4;
  const int b = bh >> 3, h = bh & 7;
  for (int i = tid; i < 2048; i += 256) {
    const int j = i >> 6, d = i & 63;
    Ks[j][d] = treeK[((size_t)bh * 32 + j) * 64 + d];
    Vs[j][d] = treeV[((size_t)bh * 32 + j) * 64 + d];
  }
  {
    const int w = tid >> 6, d = tid & 63;
    qs[w][d] = qkv[((size_t)(b * 512) + lq0 + w) * 1536 + h * 64 + d];
  }
  __syncthreads();
  const int w = tid >> 6;
  const int lane = tid & 63;
  const int j = lane & 31;
  float sc = 0.f;
#pragma unroll
  for (int d = 0; d < 64; ++d) sc = __fmaf_rn(qs[w][d], Ks[j][d], sc);
  sc = fmul32(sc, 0.125f);
  float m = sc;
#pragma unroll
  for (int k = 1; k < 32; k <<= 1) m = fmaxf(m, __shfl_xor(m, k));
  float p = expf(fsub32(sc, m));
  float sum = p;
#pragma unroll
  for (int k = 1; k < 32; k <<= 1) sum += __shfl_xor(sum, k);
  p = fdiv32(p, sum);
  float acc = 0.f;
#pragma unroll
  for (int jj = 0; jj < 32; ++jj)
    acc = __fmaf_rn(__shfl(p, jj), Vs[jj][lane], acc);
  attn[((size_t)(b * 512) + lq0 + w) * 512 + h * 64 + lane] = acc;
}

// ---------------- linear interpolation 512 -> 4096 rows ----------------
__global__ __launch_bounds__(256) void k_interp(
    const float* __restrict__ rows, float* __restrict__ out) {
  const int wid = blockIdx.x * 4 + (threadIdx.x >> 6);  // b*4096+s
  const int lane = threadIdx.x & 63;
  const int b = wid >> 12;
  const int s = wid & 4095;
  const double src = fmax(((double)s + 0.5) * 0.125 - 0.5, 0.0);
  const int i0 = (int)src;
  const int i1 = min(i0 + 1, 511);
  const double w1 = src - (double)i0;
  const double w0 = 1.0 - w1;
  const size_t r0 = ((size_t)b * 512 + i0) * 512;
  const size_t r1 = ((size_t)b * 512 + i1) * 512;
  const size_t o = (size_t)wid * 512;
#pragma unroll
  for (int k = 0; k < 2; ++k) {
    const int c4 = lane + 64 * k;
    const float4 a = *reinterpret_cast<const float4*>(&rows[r0 + (size_t)c4 * 4]);
    const float4 c = *reinterpret_cast<const float4*>(&rows[r1 + (size_t)c4 * 4]);
    float4 r;
    r.x = (float)((double)a.x * w0 + (double)c.x * w1);
    r.y = (float)((double)a.y * w0 + (double)c.y * w1);
    r.z = (float)((double)a.z * w0 + (double)c.z * w1);
    r.w = (float)((double)a.w * w0 + (double)c.w * w1);
    *reinterpret_cast<float4*>(&out[o + (size_t)c4 * 4]) = r;
  }
}

extern "C" void kernel_launch(void* const* d_in, const int* in_sizes, int n_in,
                              void* d_out, int out_size, void* d_ws, size_t ws_size,
                              hipStream_t stream) {
  const int*   text    = (const int*)d_in[0];
  const float* pe      = (const float*)d_in[1];
  const float* id_w    = (const float*)d_in[2];
  const float* id_b    = (const float*)d_in[3];
  const float* eg      = (const float*)d_in[4];
  const float* ebeta   = (const float*)d_in[5];
  const float* sub_w   = (const float*)d_in[6];
  const float* sub_b   = (const float*)d_in[7];
  const float* sub_th  = (const float*)d_in[8];
  const float* sub_ng  = (const float*)d_in[11];
  const float* sub_nb  = (const float*)d_in[12];
  const float* word_w  = (const float*)d_in[13];
  const float* word_b  = (const float*)d_in[14];
  const float* word_th = (const float*)d_in[15];
  const float* word_ng = (const float*)d_in[18];
  const float* word_nb = (const float*)d_in[19];
  const float* qkv_w   = (const float*)d_in[20];
  const float* qkv_b   = (const float*)d_in[21];
  const float* node_w  = (const float*)d_in[22];
  const float* node_b  = (const float*)d_in[23];
  const float* node_th = (const float*)d_in[24];
  const float* node_tau= (const float*)d_in[25];
  const float* node_vr = (const float*)d_in[26];
  const float* out_ng  = (const float*)d_in[27];
  const float* out_nb  = (const float*)d_in[28];

  float* O   = (float*)d_out;   // 67,108,864 floats
  float* WSF = (float*)d_ws;

  // d_out regions (floats)
  float* FU  = O;               // fused1 [0 : 33554432)
  float* GZ1 = O + 33554432;    // sub gated proj [33554432 : 67108864)
  float* WD  = O + 33554432;    // word [33554432 : 41943040)
  float* GZ2 = O + 41943040;    // word gated proj (dead before qkv write)
  float* QKV = O + 41943040;    // qkv  [41943040 : 67108864)

  // ws regions (floats)
  float* W1   = WSF;            // [0 : 8388608)
  float* NWT  = WSF + 8388608;  // 61440
  float* TK   = WSF + 8450048;  // 524288
  float* TV   = WSF + 8974336;  // 524288
  float* ROWS = WSF + 9498624;  // 8388608
  float* WTs  = WSF + 17887232; // 262144  (sub_w^T  [512][512])
  float* WTw  = WSF + 18149376; // 262144  (word_w^T [512][512])
  float* WTq  = WSF + 18411520; // 786432  (qkv_w^T  [512][1536])
  float* ATT  = WSF;            // reuses W1 (dead after word LN)

  // 0. weight transposes (independent of activations)
  k_transpose_w<<<dim3(16, 16), 256, 0, stream>>>(sub_w, WTs, 512);
  k_transpose_w<<<dim3(16, 16), 256, 0, stream>>>(word_w, WTw, 512);
  k_transpose_w<<<dim3(48, 16), 256, 0, stream>>>(qkv_w, WTq, 1536);
  k_transpose_nw<<<240, 256, 0, stream>>>(node_w, NWT);
  // 1. embed + LN + pool2 -> FU
  k_embed<<<16384, 256, 0, stream>>>(text, pe, id_w, id_b, eg, ebeta, FU);
  // 2. GZ1 = gate(FU @ sub_w^T + b)
  k_gemm_nt<<<dim3(1024, 2), 512, 0, stream>>>(FU, WTs, sub_b, sub_th, GZ1, 512);
  // 3. W1 = pool4(LN(GZ1 + FU))  — sub never materialized
  k_add_ln_pool<<<16384, 256, 0, stream>>>(GZ1, FU, sub_ng, sub_nb, W1);
  // 4. GZ2 = gate(W1 @ word_w^T + b)
  k_gemm_nt<<<dim3(256, 2), 512, 0, stream>>>(W1, WTw, word_b, word_th, GZ2, 512);
  // 5. word = LN(GZ2 + W1) -> WD
  k_add_ln<<<4096, 256, 0, stream>>>(GZ2, W1, word_ng, word_nb, WD, 16384);
  // 6. QKV = WD @ qkv_w^T + b
  k_gemm_nt<<<dim3(256, 6), 512, 0, stream>>>(WD, WTq, qkv_b, nullptr, QKV, 1536);
  // 7. fused spiking tree -> TK, TV
  k_tree<<<1024, 256, 0, stream>>>(QKV, NWT, node_b, node_th,
                                   node_tau, node_vr, TK, TV);
  // 8. attention -> ATT (reuses dead W1 space)
  k_attn<<<32768, 256, 0, stream>>>(QKV, TK, TV, ATT);
  // 9. rows = LN(ATT + word) -> ROWS
  k_add_ln<<<4096, 256, 0, stream>>>(ATT, WD, out_ng, out_nb, ROWS, 16384);
  // 10. interpolate 512 -> 4096 rows, full fp32 d_out overwrite
  k_interp<<<32768, 256, 0, stream>>>(ROWS, O);
}

// Round 17
// 1794.402 us; speedup vs baseline: 5.4706x; 1.0399x over previous
//
#include <hip/hip_runtime.h>
#include <math.h>

// ---------------------------------------------------------------------------
// TreeTextEmbed — numpy-faithful fp32 pipeline, round 17.
// NUMERICS FROZEN (r7-r16 passed, absmax 0.015625): ascending-k fp32 FMA chain
// w/ 384/128 panels; AVX512 pairwise mean; baseline-SSE einsum; __f*_rn
// elementwise in np op order.
// PERF vs r16 (GEMM LDS-pipe-bound: 96 LDS instr/wave-tile, 32 of them X
// broadcasts delivering 32B each; occupancy 1 block/CU at 80KB LDS):
//   - X reads moved OFF the LDS pipe: plain per-lane global_load_dwordx4
//     from L2 (X tiles are 8KB/block, L2-resident; 2-addr broadcast pattern
//     coalesces to 2 lines). LDS = W only (64KB dbuf) -> 64 LDS instr/tile.
//   - __syncthreads barriers (r12==r13 proved equivalent; counted vmcnt
//     would be corrupted by inner-loop X vmem ops).
// ---------------------------------------------------------------------------

__device__ __forceinline__ float fadd32(float a, float b) { return __fadd_rn(a, b); }
__device__ __forceinline__ float fmul32(float a, float b) { return __fmul_rn(a, b); }
__device__ __forceinline__ float fsub32(float a, float b) { return __fsub_rn(a, b); }
__device__ __forceinline__ float fdiv32(float a, float b) { return __fdiv_rn(a, b); }

// async global->LDS, 16B per lane; LDS dest = wave-uniform base + lane*16
__device__ __forceinline__ void gload16(const float* g, float* l) {
  __builtin_amdgcn_global_load_lds(
      (const __attribute__((address_space(1))) void*)g,
      (__attribute__((address_space(3))) void*)l, 16, 0, 0);
}

// numpy pairwise sum of contiguous 512 floats, AVX512 model (bit-frozen).
__device__ __forceinline__ float np_pairwise512(const float* row, int lane) {
  const int L = lane >> 4, j = lane & 15;
  const float* p = row + 128 * L + j;
  const float r0 = p[0],  r1 = p[16], r2 = p[32],  r3 = p[48];
  const float r4 = p[64], r5 = p[80], r6 = p[96],  r7 = p[112];
  float v = fadd32(fadd32(fadd32(r0, r1), fadd32(r2, r3)),
                   fadd32(fadd32(r4, r5), fadd32(r6, r7)));
  v = fadd32(v, __shfl_xor(v, 8));
  v = fadd32(v, __shfl_xor(v, 4));
  v = fadd32(v, __shfl_xor(v, 2));
  v = fadd32(v, __shfl_xor(v, 1));
  v = fadd32(v, __shfl_xor(v, 16));
  v = fadd32(v, __shfl_xor(v, 32));
  return v;
}

// ---------------- K1: embed + LN + pool2 (float4; per-element ops frozen) ----
__global__ __launch_bounds__(256) void k_embed(
    const int* __restrict__ text, const float* __restrict__ pe,
    const float* __restrict__ id_w, const float* __restrict__ id_b,
    const float* __restrict__ eg, const float* __restrict__ eb,
    float* __restrict__ fused) {
  __shared__ float rb[4][512];
  const int w = threadIdx.x >> 6;
  const int lane = threadIdx.x & 63;
  const int wid = blockIdx.x * 4 + w;  // row b*2048+t
  const int b = wid >> 11;
  const int t = wid & 2047;
  const int c0 = lane * 4, c1 = 256 + lane * 4;
  const float4 iw0 = *(const float4*)&id_w[c0], iw1 = *(const float4*)&id_w[c1];
  const float4 ib0 = *(const float4*)&id_b[c0], ib1 = *(const float4*)&id_b[c1];
  const float4 g0  = *(const float4*)&eg[c0],  g1  = *(const float4*)&eg[c1];
  const float4 e0  = *(const float4*)&eb[c0],  e1  = *(const float4*)&eb[c1];
  float4 fus0, fus1;
#pragma unroll
  for (int ss = 0; ss < 2; ++ss) {
    const int s = 2 * t + ss;
    const float idv = (float)text[b * 4096 + s];
    const float4 p0 = *(const float4*)&pe[(size_t)s * 512 + c0];
    const float4 p1 = *(const float4*)&pe[(size_t)s * 512 + c1];
    float4 x0, x1;
#pragma unroll
    for (int j = 0; j < 4; ++j) {
      (&x0.x)[j] = fadd32(fadd32(fmul32(idv, (&iw0.x)[j]), (&ib0.x)[j]), (&p0.x)[j]);
      (&x1.x)[j] = fadd32(fadd32(fmul32(idv, (&iw1.x)[j]), (&ib1.x)[j]), (&p1.x)[j]);
    }
    *(float4*)&rb[w][c0] = x0;
    *(float4*)&rb[w][c1] = x1;
    const float m = fmul32(np_pairwise512(rb[w], lane), 1.f / 512.f);
    float4 d0, d1, q0, q1;
#pragma unroll
    for (int j = 0; j < 4; ++j) {
      (&d0.x)[j] = fsub32((&x0.x)[j], m);
      (&d1.x)[j] = fsub32((&x1.x)[j], m);
      (&q0.x)[j] = fmul32((&d0.x)[j], (&d0.x)[j]);
      (&q1.x)[j] = fmul32((&d1.x)[j], (&d1.x)[j]);
    }
    *(float4*)&rb[w][c0] = q0;
    *(float4*)&rb[w][c1] = q1;
    const float var = fmul32(np_pairwise512(rb[w], lane), 1.f / 512.f);
    const float sdev = __fsqrt_rn(fadd32(var, 1e-5f));
#pragma unroll
    for (int j = 0; j < 4; ++j) {
      const float l0 = fadd32(fmul32(fdiv32((&d0.x)[j], sdev), (&g0.x)[j]), (&e0.x)[j]);
      const float l1 = fadd32(fmul32(fdiv32((&d1.x)[j], sdev), (&g1.x)[j]), (&e1.x)[j]);
      if (ss) {
        (&fus0.x)[j] = fmul32(fadd32((&fus0.x)[j], l0), 0.5f);
        (&fus1.x)[j] = fmul32(fadd32((&fus1.x)[j], l1), 0.5f);
      } else {
        (&fus0.x)[j] = l0;
        (&fus1.x)[j] = l1;
      }
    }
  }
  const size_t row = (size_t)wid * 512;
  *(float4*)&fused[row + c0] = fus0;
  *(float4*)&fused[row + c1] = fus1;
}

// ---------------- tiled weight transpose: WT[k][n] = W[n][k], K=512 ----------
__global__ __launch_bounds__(256) void k_transpose_w(
    const float* __restrict__ W, float* __restrict__ WT, int Nn) {
  __shared__ float t[32][33];
  const int n0 = blockIdx.x * 32, k0 = blockIdx.y * 32;
  const int li = threadIdx.x & 31, wi = threadIdx.x >> 5;
  for (int r = wi; r < 32; r += 8)
    t[r][li] = W[(size_t)(n0 + r) * 512 + k0 + li];
  __syncthreads();
  for (int r = wi; r < 32; r += 8)
    WT[(size_t)(k0 + r) * Nn + n0 + li] = t[li][r];
}

// ---- unified np-sgemm from WT[K][N]: OUT = [gate](X @ W^T + bias)
// BM=64, BN=256, BK=32; 512 thr (8 waves); per-thread 4 rows x 8 cols.
// W in LDS (double-buffered, gload_lds); X read DIRECT from global/L2
// (per-lane dwordx4, half-wave-broadcast addresses). One __syncthreads/tile.
// Chain per element: k ascending, panels [0,384)+[384,512)  (bit-frozen).
#define GEMM_INNER(acc, buf, kbase)                                  \
  _Pragma("unroll")                                                  \
  for (int kq = 0; kq < 32; kq += 4) {                               \
    float4 xf[4];                                                    \
    _Pragma("unroll")                                                \
    for (int r = 0; r < 4; ++r)                                      \
      xf[r] = *(const float4*)&X[(bm + rg * 4 + r) * 512 + (kbase) + kq]; \
    _Pragma("unroll")                                                \
    for (int u = 0; u < 4; ++u) {                                    \
      const float4 w0 = *(const float4*)&Ws[buf][kq + u][cg * 4];    \
      const float4 w1 = *(const float4*)&Ws[buf][kq + u][128 + cg * 4]; \
      _Pragma("unroll")                                              \
      for (int r = 0; r < 4; ++r) {                                  \
        const float xv = (&xf[r].x)[u];                              \
        acc[r][0] = __fmaf_rn(xv, w0.x, acc[r][0]);                  \
        acc[r][1] = __fmaf_rn(xv, w0.y, acc[r][1]);                  \
        acc[r][2] = __fmaf_rn(xv, w0.z, acc[r][2]);                  \
        acc[r][3] = __fmaf_rn(xv, w0.w, acc[r][3]);                  \
        acc[r][4] = __fmaf_rn(xv, w1.x, acc[r][4]);                  \
        acc[r][5] = __fmaf_rn(xv, w1.y, acc[r][5]);                  \
        acc[r][6] = __fmaf_rn(xv, w1.z, acc[r][6]);                  \
        acc[r][7] = __fmaf_rn(xv, w1.w, acc[r][7]);                  \
      }                                                              \
    }                                                                \
  }

// stage one 32x256 W tile into buf: 4 gload16 per wave
#define STAGE(buf, k0)                                                        \
  {                                                                           \
    _Pragma("unroll")                                                         \
    for (int c = 0; c < 4; ++c)                                               \
      gload16(&WT[(size_t)((k0) + wvid * 4 + c) * N + bn + lane * 4],         \
              &Ws[buf][wvid * 4 + c][0]);                                     \
  }

__global__ __launch_bounds__(512) void k_gemm_nt(
    const float* __restrict__ X, const float* __restrict__ WT,
    const float* __restrict__ bias, const float* __restrict__ th,
    float* __restrict__ OUT, int N) {
  __shared__ float Ws[2][32][256];   // 64 KB — linear for gload_lds (W only)
  const int tid = threadIdx.x;
  const int wvid = tid >> 6, lane = tid & 63;
  const int rg = tid >> 5;   // 0..15 (row group, 4 rows each)
  const int cg = tid & 31;   // 0..31 (col group, 2x4 cols each)
  const size_t bm = (size_t)blockIdx.x * 64;
  const int bn = blockIdx.y * 256;

  float accA[4][8], accB[4][8];
#pragma unroll
  for (int r = 0; r < 4; ++r)
#pragma unroll
    for (int c = 0; c < 8; ++c) { accA[r][c] = 0.f; accB[r][c] = 0.f; }

  STAGE(0, 0);
  __syncthreads();
  for (int t = 0; t < 16; ++t) {
    const int cur = t & 1;
    if (t < 15) STAGE(cur ^ 1, (t + 1) * 32);
    if (t < 12) { GEMM_INNER(accA, cur, t * 32); }
    else        { GEMM_INNER(accB, cur, t * 32); }
    __syncthreads();
  }
  // epilogue: C = P1+P2; +bias; optional gate (bit-frozen sequence)
#pragma unroll
  for (int r = 0; r < 4; ++r) {
    const size_t rb = (bm + rg * 4 + r) * (size_t)N;
    float4 o0, o1;
#pragma unroll
    for (int c = 0; c < 4; ++c) {
      const int col0 = bn + cg * 4 + c;
      const int col1 = bn + 128 + cg * 4 + c;
      const float v0 = fadd32(fadd32(accA[r][c], accB[r][c]), bias[col0]);
      const float v1 = fadd32(fadd32(accA[r][4 + c], accB[r][4 + c]), bias[col1]);
      (&o0.x)[c] = th ? ((v0 >= th[col0]) ? v0 : 0.f) : v0;
      (&o1.x)[c] = th ? ((v1 >= th[col1]) ? v1 : 0.f) : v1;
    }
    *(float4*)&OUT[rb + bn + cg * 4] = o0;
    *(float4*)&OUT[rb + bn + 128 + cg * 4] = o1;
  }
}

// ---------------- residual + LN (float4; per-element ops frozen) ------------
__global__ __launch_bounds__(256) void k_add_ln(
    const float* __restrict__ A, const float* F,
    const float* __restrict__ g, const float* __restrict__ bet,
    float* O, int nrows) {
  __shared__ float zb[4][512];
  const int w = threadIdx.x >> 6;
  const int lane = threadIdx.x & 63;
  const int wid = blockIdx.x * 4 + w;
  if (wid >= nrows) return;
  const size_t row = (size_t)wid * 512;
  const int c0 = lane * 4, c1 = 256 + lane * 4;
  const float4 a0 = *(const float4*)&A[row + c0];
  const float4 a1 = *(const float4*)&A[row + c1];
  const float4 f0 = *(const float4*)&F[row + c0];
  const float4 f1 = *(const float4*)&F[row + c1];
  float4 z0, z1;
#pragma unroll
  for (int j = 0; j < 4; ++j) {
    (&z0.x)[j] = fadd32((&a0.x)[j], (&f0.x)[j]);
    (&z1.x)[j] = fadd32((&a1.x)[j], (&f1.x)[j]);
  }
  *(float4*)&zb[w][c0] = z0;
  *(float4*)&zb[w][c1] = z1;
  const float m = fmul32(np_pairwise512(zb[w], lane), 1.f / 512.f);
  float4 d0, d1, q0, q1;
#pragma unroll
  for (int j = 0; j < 4; ++j) {
    (&d0.x)[j] = fsub32((&z0.x)[j], m);
    (&d1.x)[j] = fsub32((&z1.x)[j], m);
    (&q0.x)[j] = fmul32((&d0.x)[j], (&d0.x)[j]);
    (&q1.x)[j] = fmul32((&d1.x)[j], (&d1.x)[j]);
  }
  *(float4*)&zb[w][c0] = q0;
  *(float4*)&zb[w][c1] = q1;
  const float var = fmul32(np_pairwise512(zb[w], lane), 1.f / 512.f);
  const float sdev = __fsqrt_rn(fadd32(var, 1e-5f));
  const float4 gg0 = *(const float4*)&g[c0], gg1 = *(const float4*)&g[c1];
  const float4 bb0 = *(const float4*)&bet[c0], bb1 = *(const float4*)&bet[c1];
  float4 o0, o1;
#pragma unroll
  for (int j = 0; j < 4; ++j) {
    (&o0.x)[j] = fadd32(fmul32(fdiv32((&d0.x)[j], sdev), (&gg0.x)[j]), (&bb0.x)[j]);
    (&o1.x)[j] = fadd32(fmul32(fdiv32((&d1.x)[j], sdev), (&gg1.x)[j]), (&bb1.x)[j]);
  }
  *(float4*)&O[row + c0] = o0;
  *(float4*)&O[row + c1] = o1;
}

// ---- fused residual + LN + pool4 (sub stage; sub never materialized) -------
__global__ __launch_bounds__(256) void k_add_ln_pool(
    const float* __restrict__ A, const float* __restrict__ F,
    const float* __restrict__ g, const float* __restrict__ bet,
    float* __restrict__ OUT) {
  __shared__ float zb[4][512];
  __shared__ float lnr[4][512];
  const int w = threadIdx.x >> 6;
  const int lane = threadIdx.x & 63;
  const int wid = blockIdx.x * 4 + w;
  const size_t row = (size_t)wid * 512;
  const int c0 = lane * 4, c1 = 256 + lane * 4;
  const float4 a0 = *(const float4*)&A[row + c0];
  const float4 a1 = *(const float4*)&A[row + c1];
  const float4 f0 = *(const float4*)&F[row + c0];
  const float4 f1 = *(const float4*)&F[row + c1];
  float4 z0, z1;
#pragma unroll
  for (int j = 0; j < 4; ++j) {
    (&z0.x)[j] = fadd32((&a0.x)[j], (&f0.x)[j]);
    (&z1.x)[j] = fadd32((&a1.x)[j], (&f1.x)[j]);
  }
  *(float4*)&zb[w][c0] = z0;
  *(float4*)&zb[w][c1] = z1;
  const float m = fmul32(np_pairwise512(zb[w], lane), 1.f / 512.f);
  float4 d0, d1, q0, q1;
#pragma unroll
  for (int j = 0; j < 4; ++j) {
    (&d0.x)[j] = fsub32((&z0.x)[j], m);
    (&d1.x)[j] = fsub32((&z1.x)[j], m);
    (&q0.x)[j] = fmul32((&d0.x)[j], (&d0.x)[j]);
    (&q1.x)[j] = fmul32((&d1.x)[j], (&d1.x)[j]);
  }
  *(float4*)&zb[w][c0] = q0;
  *(float4*)&zb[w][c1] = q1;
  const float var = fmul32(np_pairwise512(zb[w], lane), 1.f / 512.f);
  const float sdev = __fsqrt_rn(fadd32(var, 1e-5f));
  float4 o0, o1;
#pragma unroll
  for (int j = 0; j < 4; ++j) {
    (&o0.x)[j] = fadd32(fmul32(fdiv32((&d0.x)[j], sdev), g[c0 + j]), bet[c0 + j]);
    (&o1.x)[j] = fadd32(fmul32(fdiv32((&d1.x)[j], sdev), g[c1 + j]), bet[c1 + j]);
  }
  *(float4*)&lnr[w][c0] = o0;
  *(float4*)&lnr[w][c1] = o1;
  __syncthreads();
  if (threadIdx.x < 128) {
    const int c4 = threadIdx.x * 4;
    const float4 l0 = *(const float4*)&lnr[0][c4];
    const float4 l1 = *(const float4*)&lnr[1][c4];
    const float4 l2 = *(const float4*)&lnr[2][c4];
    const float4 l3 = *(const float4*)&lnr[3][c4];
    float4 o;
#pragma unroll
    for (int j = 0; j < 4; ++j) {
      const float s = fadd32(fadd32(fadd32((&l0.x)[j], (&l1.x)[j]), (&l2.x)[j]),
                             (&l3.x)[j]);
      (&o.x)[j] = fmul32(s, 0.25f);
    }
    *(float4*)&OUT[(size_t)blockIdx.x * 512 + c4] = o;
  }
}

// ---------------- transpose node weights: nwT[n][d][e] = nw[n][e][d] --------
__global__ __launch_bounds__(256) void k_transpose_nw(
    const float* __restrict__ nw, float* __restrict__ nwT) {
  const int idx = blockIdx.x * 256 + threadIdx.x;
  if (idx >= 15 * 4096) return;
  const int n = idx >> 12;
  const int e = (idx >> 6) & 63;
  const int d = idx & 63;
  nwT[(n << 12) + (d << 6) + e] = nw[idx];
}

// numpy einsum baseline-SSE model (bit-frozen).
#define NP_EINSUM64(inp, wp, out_)                                          \
  {                                                                         \
    float c0 = 0.f, c1 = 0.f, c2 = 0.f, c3 = 0.f;                           \
    _Pragma("unroll")                                                       \
    for (int q_ = 0; q_ < 4; ++q_) {                                        \
      const int b_ = 16 * q_;                                               \
      _Pragma("unroll")                                                     \
      for (int u_ = 3; u_ >= 0; --u_) {                                     \
        const int d0_ = b_ + 4 * u_;                                        \
        c0 = fadd32(fmul32(__shfl(inp, d0_ + 0), wp[(d0_ + 0) << 6]), c0);  \
        c1 = fadd32(fmul32(__shfl(inp, d0_ + 1), wp[(d0_ + 1) << 6]), c1);  \
        c2 = fadd32(fmul32(__shfl(inp, d0_ + 2), wp[(d0_ + 2) << 6]), c2);  \
        c3 = fadd32(fmul32(__shfl(inp, d0_ + 3), wp[(d0_ + 3) << 6]), c3);  \
      }                                                                     \
    }                                                                       \
    out_ = fadd32(fadd32(c0, c1), fadd32(c2, c3));                          \
  }

// ---------------- fused spiking tree (bit-frozen) ----------------
__global__ __launch_bounds__(256) void k_tree(
    const float* __restrict__ QKV, const float* __restrict__ nwT,
    const float* __restrict__ nb, const float* __restrict__ th,
    const float* __restrict__ tau, const float* __restrict__ vr,
    float* __restrict__ TK, float* __restrict__ TV) {
  __shared__ float st0[8][8][64];
  __shared__ float st1[4][8][64];
  __shared__ float st2[2][8][64];
  __shared__ float st3[8][64];
  __shared__ float outA[8][8][64];
  __shared__ float outB[4][8][64];
  const int tid = threadIdx.x, w = tid >> 6, lane = tid & 63;
  const int sq = blockIdx.x & 3, bh = blockIdx.x >> 2;
  const int b = bh >> 3, h = bh & 7;
  for (int pass = 0; pass < 2; ++pass) {
    const int koff = 512 + pass * 512;
    for (int r = w; r < 64; r += 4) {
      const int n = r >> 3, sl = r & 7, sg = sq * 8 + sl;
      const float inp = QKV[((size_t)(b * 512 + n * 32 + sg)) * 1536 + koff + h * 64 + lane];
      const int node = 7 + n, pc = node * 64 + lane;
      const float* wp = nwT + node * 4096 + lane;
      float tot;
      NP_EINSUM64(inp, wp, tot);
      const float proj = fadd32(tot, nb[pc]);
      const float v = pass ? fadd32(fmul32(tau[pc], st0[n][sl][lane]), proj) : proj;
      const bool sp = v >= th[pc];
      if (!pass) st0[n][sl][lane] = sp ? vr[pc] : v;
      outA[n][sl][lane] = sp ? proj : 0.f;
    }
    __syncthreads();
    for (int r = w; r < 32; r += 4) {
      const int n = r >> 3, sl = r & 7;
      const float inp = fmul32(0.5f, fadd32(outA[2 * n][sl][lane], outA[2 * n + 1][sl][lane]));
      const int node = 3 + n, pc = node * 64 + lane;
      const float* wp = nwT + node * 4096 + lane;
      float tot;
      NP_EINSUM64(inp, wp, tot);
      const float proj = fadd32(tot, nb[pc]);
      const float v = pass ? fadd32(fmul32(tau[pc], st1[n][sl][lane]), proj) : proj;
      const bool sp = v >= th[pc];
      if (!pass) st1[n][sl][lane] = sp ? vr[pc] : v;
      outB[n][sl][lane] = sp ? proj : 0.f;
    }
    __syncthreads();
    for (int r = w; r < 16; r += 4) {
      const int n = r >> 3, sl = r & 7;
      const float inp = fmul32(0.5f, fadd32(outB[2 * n][sl][lane], outB[2 * n + 1][sl][lane]));
      const int node = 1 + n, pc = node * 64 + lane;
      const float* wp = nwT + node * 4096 + lane;
      float tot;
      NP_EINSUM64(inp, wp, tot);
      const float proj = fadd32(tot, nb[pc]);
      const float v = pass ? fadd32(fmul32(tau[pc], st2[n][sl][lane]), proj) : proj;
      const bool sp = v >= th[pc];
      if (!pass) st2[n][sl][lane] = sp ? vr[pc] : v;
      outA[n][sl][lane] = sp ? proj : 0.f;
    }
    __syncthreads();
    for (int r = w; r < 8; r += 4) {
      const int sl = r & 7, sg = sq * 8 + sl;
      const float inp = fmul32(0.5f, fadd32(outA[0][sl][lane], outA[1][sl][lane]));
      const int pc = lane;
      const float* wp = nwT + lane;
      float tot;
      NP_EINSUM64(inp, wp, tot);
      const float proj = fadd32(tot, nb[pc]);
      const float v = pass ? fadd32(fmul32(tau[pc], st3[sl][lane]), proj) : proj;
      const bool sp = v >= th[pc];
      if (!pass) st3[sl][lane] = sp ? vr[pc] : v;
      float* dst = pass ? TV : TK;
      dst[((size_t)bh * 32 + sg) * 64 + lane] = sp ? proj : 0.f;
    }
    __syncthreads();
  }
}

// ---------------- attention (post-gate, relaxed; fp32 chains) ----------------
__global__ __launch_bounds__(256) void k_attn(
    const float* __restrict__ qkv, const float* __restrict__ treeK,
    const float* __restrict__ treeV, float* __restrict__ attn) {
  __shared__ float Ks[32][65];
  __shared__ float Vs[32][64];
  __shared__ float qs[4][64];
  const int tid = threadIdx.x;
  const int bh = blockIdx.x >> 7;
  const int lq0 = (blockIdx.x & 127) * 4;
  const int b = bh >> 3, h = bh & 7;
  for (int i = tid; i < 2048; i += 256) {
    const int j = i >> 6, d = i & 63;
    Ks[j][d] = treeK[((size_t)bh * 32 + j) * 64 + d];
    Vs[j][d] = treeV[((size_t)bh * 32 + j) * 64 + d];
  }
  {
    const int w = tid >> 6, d = tid & 63;
    qs[w][d] = qkv[((size_t)(b * 512) + lq0 + w) * 1536 + h * 64 + d];
  }
  __syncthreads();
  const int w = tid >> 6;
  const int lane = tid & 63;
  const int j = lane & 31;
  float sc = 0.f;
#pragma unroll
  for (int d = 0; d < 64; ++d) sc = __fmaf_rn(qs[w][d], Ks[j][d], sc);
  sc = fmul32(sc, 0.125f);
  float m = sc;
#pragma unroll
  for (int k = 1; k < 32; k <<= 1) m = fmaxf(m, __shfl_xor(m, k));
  float p = expf(fsub32(sc, m));
  float sum = p;
#pragma unroll
  for (int k = 1; k < 32; k <<= 1) sum += __shfl_xor(sum, k);
  p = fdiv32(p, sum);
  float acc = 0.f;
#pragma unroll
  for (int jj = 0; jj < 32; ++jj)
    acc = __fmaf_rn(__shfl(p, jj), Vs[jj][lane], acc);
  attn[((size_t)(b * 512) + lq0 + w) * 512 + h * 64 + lane] = acc;
}

// ---------------- linear interpolation 512 -> 4096 rows ----------------
__global__ __launch_bounds__(256) void k_interp(
    const float* __restrict__ rows, float* __restrict__ out) {
  const int wid = blockIdx.x * 4 + (threadIdx.x >> 6);  // b*4096+s
  const int lane = threadIdx.x & 63;
  const int b = wid >> 12;
  const int s = wid & 4095;
  const double src = fmax(((double)s + 0.5) * 0.125 - 0.5, 0.0);
  const int i0 = (int)src;
  const int i1 = min(i0 + 1, 511);
  const double w1 = src - (double)i0;
  const double w0 = 1.0 - w1;
  const size_t r0 = ((size_t)b * 512 + i0) * 512;
  const size_t r1 = ((size_t)b * 512 + i1) * 512;
  const size_t o = (size_t)wid * 512;
#pragma unroll
  for (int k = 0; k < 2; ++k) {
    const int c4 = lane + 64 * k;
    const float4 a = *reinterpret_cast<const float4*>(&rows[r0 + (size_t)c4 * 4]);
    const float4 c = *reinterpret_cast<const float4*>(&rows[r1 + (size_t)c4 * 4]);
    float4 r;
    r.x = (float)((double)a.x * w0 + (double)c.x * w1);
    r.y = (float)((double)a.y * w0 + (double)c.y * w1);
    r.z = (float)((double)a.z * w0 + (double)c.z * w1);
    r.w = (float)((double)a.w * w0 + (double)c.w * w1);
    *reinterpret_cast<float4*>(&out[o + (size_t)c4 * 4]) = r;
  }
}

extern "C" void kernel_launch(void* const* d_in, const int* in_sizes, int n_in,
                              void* d_out, int out_size, void* d_ws, size_t ws_size,
                              hipStream_t stream) {
  const int*   text    = (const int*)d_in[0];
  const float* pe      = (const float*)d_in[1];
  const float* id_w    = (const float*)d_in[2];
  const float* id_b    = (const float*)d_in[3];
  const float* eg      = (const float*)d_in[4];
  const float* ebeta   = (const float*)d_in[5];
  const float* sub_w   = (const float*)d_in[6];
  const float* sub_b   = (const float*)d_in[7];
  const float* sub_th  = (const float*)d_in[8];
  const float* sub_ng  = (const float*)d_in[11];
  const float* sub_nb  = (const float*)d_in[12];
  const float* word_w  = (const float*)d_in[13];
  const float* word_b  = (const float*)d_in[14];
  const float* word_th = (const float*)d_in[15];
  const float* word_ng = (const float*)d_in[18];
  const float* word_nb = (const float*)d_in[19];
  const float* qkv_w   = (const float*)d_in[20];
  const float* qkv_b   = (const float*)d_in[21];
  const float* node_w  = (const float*)d_in[22];
  const float* node_b  = (const float*)d_in[23];
  const float* node_th = (const float*)d_in[24];
  const float* node_tau= (const float*)d_in[25];
  const float* node_vr = (const float*)d_in[26];
  const float* out_ng  = (const float*)d_in[27];
  const float* out_nb  = (const float*)d_in[28];

  float* O   = (float*)d_out;   // 67,108,864 floats
  float* WSF = (float*)d_ws;

  // d_out regions (floats)
  float* FU  = O;               // fused1 [0 : 33554432)
  float* GZ1 = O + 33554432;    // sub gated proj [33554432 : 67108864)
  float* WD  = O + 33554432;    // word [33554432 : 41943040)
  float* GZ2 = O + 41943040;    // word gated proj (dead before qkv write)
  float* QKV = O + 41943040;    // qkv  [41943040 : 67108864)

  // ws regions (floats)
  float* W1   = WSF;            // [0 : 8388608)
  float* NWT  = WSF + 8388608;  // 61440
  float* TK   = WSF + 8450048;  // 524288
  float* TV   = WSF + 8974336;  // 524288
  float* ROWS = WSF + 9498624;  // 8388608
  float* WTs  = WSF + 17887232; // 262144  (sub_w^T  [512][512])
  float* WTw  = WSF + 18149376; // 262144  (word_w^T [512][512])
  float* WTq  = WSF + 18411520; // 786432  (qkv_w^T  [512][1536])
  float* ATT  = WSF;            // reuses W1 (dead after word LN)

  // 0. weight transposes (independent of activations)
  k_transpose_w<<<dim3(16, 16), 256, 0, stream>>>(sub_w, WTs, 512);
  k_transpose_w<<<dim3(16, 16), 256, 0, stream>>>(word_w, WTw, 512);
  k_transpose_w<<<dim3(48, 16), 256, 0, stream>>>(qkv_w, WTq, 1536);
  k_transpose_nw<<<240, 256, 0, stream>>>(node_w, NWT);
  // 1. embed + LN + pool2 -> FU
  k_embed<<<16384, 256, 0, stream>>>(text, pe, id_w, id_b, eg, ebeta, FU);
  // 2. GZ1 = gate(FU @ sub_w^T + b)
  k_gemm_nt<<<dim3(1024, 2), 512, 0, stream>>>(FU, WTs, sub_b, sub_th, GZ1, 512);
  // 3. W1 = pool4(LN(GZ1 + FU))  — sub never materialized
  k_add_ln_pool<<<16384, 256, 0, stream>>>(GZ1, FU, sub_ng, sub_nb, W1);
  // 4. GZ2 = gate(W1 @ word_w^T + b)
  k_gemm_nt<<<dim3(256, 2), 512, 0, stream>>>(W1, WTw, word_b, word_th, GZ2, 512);
  // 5. word = LN(GZ2 + W1) -> WD
  k_add_ln<<<4096, 256, 0, stream>>>(GZ2, W1, word_ng, word_nb, WD, 16384);
  // 6. QKV = WD @ qkv_w^T + b
  k_gemm_nt<<<dim3(256, 6), 512, 0, stream>>>(WD, WTq, qkv_b, nullptr, QKV, 1536);
  // 7. fused spiking tree -> TK, TV
  k_tree<<<1024, 256, 0, stream>>>(QKV, NWT, node_b, node_th,
                                   node_tau, node_vr, TK, TV);
  // 8. attention -> ATT (reuses dead W1 space)
  k_attn<<<32768, 256, 0, stream>>>(QKV, TK, TV, ATT);
  // 9. rows = LN(ATT + word) -> ROWS
  k_add_ln<<<4096, 256, 0, stream>>>(ATT, WD, out_ng, out_nb, ROWS, 16384);
  // 10. interpolate 512 -> 4096 rows, full fp32 d_out overwrite
  k_interp<<<32768, 256, 0, stream>>>(ROWS, O);
}

// Round 18
// 1758.646 us; speedup vs baseline: 5.5818x; 1.0203x over previous
//
#include <hip/hip_runtime.h>
#include <math.h>

// ---------------------------------------------------------------------------
// TreeTextEmbed — numpy-faithful fp32 pipeline, round 18.
// NUMERICS FROZEN (r7-r17 passed, absmax 0.015625): ascending-k fp32 FMA chain
// w/ 384/128 panels; AVX512 pairwise mean; baseline-SSE einsum; __f*_rn
// elementwise in np op order.
// PERF vs r17 (GEMM co-limited by VALU issue: 1024 scalar v_fma wave-instr
// per wave-tile at VALUBusy 57%):
//   - inner loop uses v_pk_fma_f32 (VOP3P packed fp32 FMA): one instruction
//     = two independent IEEE RN fp32 FMAs -> 512 FMA instr/tile. Adjacent
//     output columns packed; each element keeps its own ascending-k chain
//     (bit-exact, pk lanes == __fmaf_rn).
//   - everything else identical to r17 (X direct from L2, W-only LDS dbuf).
// ---------------------------------------------------------------------------

typedef float f32x2 __attribute__((ext_vector_type(2)));

__device__ __forceinline__ float fadd32(float a, float b) { return __fadd_rn(a, b); }
__device__ __forceinline__ float fmul32(float a, float b) { return __fmul_rn(a, b); }
__device__ __forceinline__ float fsub32(float a, float b) { return __fsub_rn(a, b); }
__device__ __forceinline__ float fdiv32(float a, float b) { return __fdiv_rn(a, b); }

// packed fp32 FMA: d = a*b + d (two independent IEEE RN fp32 ops)
__device__ __forceinline__ void pkfma(f32x2& d, f32x2 a, f32x2 b) {
  asm("v_pk_fma_f32 %0, %1, %2, %0" : "+v"(d) : "v"(a), "v"(b));
}

// async global->LDS, 16B per lane; LDS dest = wave-uniform base + lane*16
__device__ __forceinline__ void gload16(const float* g, float* l) {
  __builtin_amdgcn_global_load_lds(
      (const __attribute__((address_space(1))) void*)g,
      (__attribute__((address_space(3))) void*)l, 16, 0, 0);
}

// numpy pairwise sum of contiguous 512 floats, AVX512 model (bit-frozen).
__device__ __forceinline__ float np_pairwise512(const float* row, int lane) {
  const int L = lane >> 4, j = lane & 15;
  const float* p = row + 128 * L + j;
  const float r0 = p[0],  r1 = p[16], r2 = p[32],  r3 = p[48];
  const float r4 = p[64], r5 = p[80], r6 = p[96],  r7 = p[112];
  float v = fadd32(fadd32(fadd32(r0, r1), fadd32(r2, r3)),
                   fadd32(fadd32(r4, r5), fadd32(r6, r7)));
  v = fadd32(v, __shfl_xor(v, 8));
  v = fadd32(v, __shfl_xor(v, 4));
  v = fadd32(v, __shfl_xor(v, 2));
  v = fadd32(v, __shfl_xor(v, 1));
  v = fadd32(v, __shfl_xor(v, 16));
  v = fadd32(v, __shfl_xor(v, 32));
  return v;
}

// ---------------- K1: embed + LN + pool2 (float4; per-element ops frozen) ----
__global__ __launch_bounds__(256) void k_embed(
    const int* __restrict__ text, const float* __restrict__ pe,
    const float* __restrict__ id_w, const float* __restrict__ id_b,
    const float* __restrict__ eg, const float* __restrict__ eb,
    float* __restrict__ fused) {
  __shared__ float rb[4][512];
  const int w = threadIdx.x >> 6;
  const int lane = threadIdx.x & 63;
  const int wid = blockIdx.x * 4 + w;  // row b*2048+t
  const int b = wid >> 11;
  const int t = wid & 2047;
  const int c0 = lane * 4, c1 = 256 + lane * 4;
  const float4 iw0 = *(const float4*)&id_w[c0], iw1 = *(const float4*)&id_w[c1];
  const float4 ib0 = *(const float4*)&id_b[c0], ib1 = *(const float4*)&id_b[c1];
  const float4 g0  = *(const float4*)&eg[c0],  g1  = *(const float4*)&eg[c1];
  const float4 e0  = *(const float4*)&eb[c0],  e1  = *(const float4*)&eb[c1];
  float4 fus0, fus1;
#pragma unroll
  for (int ss = 0; ss < 2; ++ss) {
    const int s = 2 * t + ss;
    const float idv = (float)text[b * 4096 + s];
    const float4 p0 = *(const float4*)&pe[(size_t)s * 512 + c0];
    const float4 p1 = *(const float4*)&pe[(size_t)s * 512 + c1];
    float4 x0, x1;
#pragma unroll
    for (int j = 0; j < 4; ++j) {
      (&x0.x)[j] = fadd32(fadd32(fmul32(idv, (&iw0.x)[j]), (&ib0.x)[j]), (&p0.x)[j]);
      (&x1.x)[j] = fadd32(fadd32(fmul32(idv, (&iw1.x)[j]), (&ib1.x)[j]), (&p1.x)[j]);
    }
    *(float4*)&rb[w][c0] = x0;
    *(float4*)&rb[w][c1] = x1;
    const float m = fmul32(np_pairwise512(rb[w], lane), 1.f / 512.f);
    float4 d0, d1, q0, q1;
#pragma unroll
    for (int j = 0; j < 4; ++j) {
      (&d0.x)[j] = fsub32((&x0.x)[j], m);
      (&d1.x)[j] = fsub32((&x1.x)[j], m);
      (&q0.x)[j] = fmul32((&d0.x)[j], (&d0.x)[j]);
      (&q1.x)[j] = fmul32((&d1.x)[j], (&d1.x)[j]);
    }
    *(float4*)&rb[w][c0] = q0;
    *(float4*)&rb[w][c1] = q1;
    const float var = fmul32(np_pairwise512(rb[w], lane), 1.f / 512.f);
    const float sdev = __fsqrt_rn(fadd32(var, 1e-5f));
#pragma unroll
    for (int j = 0; j < 4; ++j) {
      const float l0 = fadd32(fmul32(fdiv32((&d0.x)[j], sdev), (&g0.x)[j]), (&e0.x)[j]);
      const float l1 = fadd32(fmul32(fdiv32((&d1.x)[j], sdev), (&g1.x)[j]), (&e1.x)[j]);
      if (ss) {
        (&fus0.x)[j] = fmul32(fadd32((&fus0.x)[j], l0), 0.5f);
        (&fus1.x)[j] = fmul32(fadd32((&fus1.x)[j], l1), 0.5f);
      } else {
        (&fus0.x)[j] = l0;
        (&fus1.x)[j] = l1;
      }
    }
  }
  const size_t row = (size_t)wid * 512;
  *(float4*)&fused[row + c0] = fus0;
  *(float4*)&fused[row + c1] = fus1;
}

// ---------------- tiled weight transpose: WT[k][n] = W[n][k], K=512 ----------
__global__ __launch_bounds__(256) void k_transpose_w(
    const float* __restrict__ W, float* __restrict__ WT, int Nn) {
  __shared__ float t[32][33];
  const int n0 = blockIdx.x * 32, k0 = blockIdx.y * 32;
  const int li = threadIdx.x & 31, wi = threadIdx.x >> 5;
  for (int r = wi; r < 32; r += 8)
    t[r][li] = W[(size_t)(n0 + r) * 512 + k0 + li];
  __syncthreads();
  for (int r = wi; r < 32; r += 8)
    WT[(size_t)(k0 + r) * Nn + n0 + li] = t[li][r];
}

// ---- unified np-sgemm from WT[K][N]: OUT = [gate](X @ W^T + bias)
// BM=64, BN=256, BK=32; 512 thr (8 waves); per-thread 4 rows x 8 cols
// (4 col-PAIRS via v_pk_fma_f32). W in LDS (dbuf, gload_lds); X direct
// from global/L2. One __syncthreads per tile.
// Chain per element: k ascending, panels [0,384)+[384,512)  (bit-frozen).
#define GEMM_INNER(acc, buf, kbase)                                  \
  _Pragma("unroll")                                                  \
  for (int kq = 0; kq < 32; kq += 4) {                               \
    float4 xf[4];                                                    \
    _Pragma("unroll")                                                \
    for (int r = 0; r < 4; ++r)                                      \
      xf[r] = *(const float4*)&X[(bm + rg * 4 + r) * 512 + (kbase) + kq]; \
    _Pragma("unroll")                                                \
    for (int u = 0; u < 4; ++u) {                                    \
      const float4 w0 = *(const float4*)&Ws[buf][kq + u][cg * 4];    \
      const float4 w1 = *(const float4*)&Ws[buf][kq + u][128 + cg * 4]; \
      const f32x2 wp0 = {w0.x, w0.y}, wp1 = {w0.z, w0.w};            \
      const f32x2 wp2 = {w1.x, w1.y}, wp3 = {w1.z, w1.w};            \
      _Pragma("unroll")                                              \
      for (int r = 0; r < 4; ++r) {                                  \
        const float xv = (&xf[r].x)[u];                              \
        const f32x2 xv2 = {xv, xv};                                  \
        pkfma(acc[r][0], xv2, wp0);                                  \
        pkfma(acc[r][1], xv2, wp1);                                  \
        pkfma(acc[r][2], xv2, wp2);                                  \
        pkfma(acc[r][3], xv2, wp3);                                  \
      }                                                              \
    }                                                                \
  }

// stage one 32x256 W tile into buf: 4 gload16 per wave
#define STAGE(buf, k0)                                                        \
  {                                                                           \
    _Pragma("unroll")                                                         \
    for (int c = 0; c < 4; ++c)                                               \
      gload16(&WT[(size_t)((k0) + wvid * 4 + c) * N + bn + lane * 4],         \
              &Ws[buf][wvid * 4 + c][0]);                                     \
  }

__global__ __launch_bounds__(512) void k_gemm_nt(
    const float* __restrict__ X, const float* __restrict__ WT,
    const float* __restrict__ bias, const float* __restrict__ th,
    float* __restrict__ OUT, int N) {
  __shared__ float Ws[2][32][256];   // 64 KB — linear for gload_lds (W only)
  const int tid = threadIdx.x;
  const int wvid = tid >> 6, lane = tid & 63;
  const int rg = tid >> 5;   // 0..15 (row group, 4 rows each)
  const int cg = tid & 31;   // 0..31 (col group, 2x4 cols each)
  const size_t bm = (size_t)blockIdx.x * 64;
  const int bn = blockIdx.y * 256;

  f32x2 accA[4][4], accB[4][4];
#pragma unroll
  for (int r = 0; r < 4; ++r)
#pragma unroll
    for (int c = 0; c < 4; ++c) {
      accA[r][c] = (f32x2){0.f, 0.f};
      accB[r][c] = (f32x2){0.f, 0.f};
    }

  STAGE(0, 0);
  __syncthreads();
  for (int t = 0; t < 16; ++t) {
    const int cur = t & 1;
    if (t < 15) STAGE(cur ^ 1, (t + 1) * 32);
    if (t < 12) { GEMM_INNER(accA, cur, t * 32); }
    else        { GEMM_INNER(accB, cur, t * 32); }
    __syncthreads();
  }
  // epilogue: C = P1+P2; +bias; optional gate (bit-frozen sequence)
  // acc pair j covers cols {2j, 2j+1} within each col-quad group:
  // j=0,1 -> cols bn+cg*4+{0..3}; j=2,3 -> cols bn+128+cg*4+{0..3}.
#pragma unroll
  for (int r = 0; r < 4; ++r) {
    const size_t rb = (bm + rg * 4 + r) * (size_t)N;
    float a8[8] = {accA[r][0].x, accA[r][0].y, accA[r][1].x, accA[r][1].y,
                   accA[r][2].x, accA[r][2].y, accA[r][3].x, accA[r][3].y};
    float b8[8] = {accB[r][0].x, accB[r][0].y, accB[r][1].x, accB[r][1].y,
                   accB[r][2].x, accB[r][2].y, accB[r][3].x, accB[r][3].y};
    float4 o0, o1;
#pragma unroll
    for (int c = 0; c < 4; ++c) {
      const int col0 = bn + cg * 4 + c;
      const int col1 = bn + 128 + cg * 4 + c;
      const float v0 = fadd32(fadd32(a8[c], b8[c]), bias[col0]);
      const float v1 = fadd32(fadd32(a8[4 + c], b8[4 + c]), bias[col1]);
      (&o0.x)[c] = th ? ((v0 >= th[col0]) ? v0 : 0.f) : v0;
      (&o1.x)[c] = th ? ((v1 >= th[col1]) ? v1 : 0.f) : v1;
    }
    *(float4*)&OUT[rb + bn + cg * 4] = o0;
    *(float4*)&OUT[rb + bn + 128 + cg * 4] = o1;
  }
}

// ---------------- residual + LN (float4; per-element ops frozen) ------------
__global__ __launch_bounds__(256) void k_add_ln(
    const float* __restrict__ A, const float* F,
    const float* __restrict__ g, const float* __restrict__ bet,
    float* O, int nrows) {
  __shared__ float zb[4][512];
  const int w = threadIdx.x >> 6;
  const int lane = threadIdx.x & 63;
  const int wid = blockIdx.x * 4 + w;
  if (wid >= nrows) return;
  const size_t row = (size_t)wid * 512;
  const int c0 = lane * 4, c1 = 256 + lane * 4;
  const float4 a0 = *(const float4*)&A[row + c0];
  const float4 a1 = *(const float4*)&A[row + c1];
  const float4 f0 = *(const float4*)&F[row + c0];
  const float4 f1 = *(const float4*)&F[row + c1];
  float4 z0, z1;
#pragma unroll
  for (int j = 0; j < 4; ++j) {
    (&z0.x)[j] = fadd32((&a0.x)[j], (&f0.x)[j]);
    (&z1.x)[j] = fadd32((&a1.x)[j], (&f1.x)[j]);
  }
  *(float4*)&zb[w][c0] = z0;
  *(float4*)&zb[w][c1] = z1;
  const float m = fmul32(np_pairwise512(zb[w], lane), 1.f / 512.f);
  float4 d0, d1, q0, q1;
#pragma unroll
  for (int j = 0; j < 4; ++j) {
    (&d0.x)[j] = fsub32((&z0.x)[j], m);
    (&d1.x)[j] = fsub32((&z1.x)[j], m);
    (&q0.x)[j] = fmul32((&d0.x)[j], (&d0.x)[j]);
    (&q1.x)[j] = fmul32((&d1.x)[j], (&d1.x)[j]);
  }
  *(float4*)&zb[w][c0] = q0;
  *(float4*)&zb[w][c1] = q1;
  const float var = fmul32(np_pairwise512(zb[w], lane), 1.f / 512.f);
  const float sdev = __fsqrt_rn(fadd32(var, 1e-5f));
  const float4 gg0 = *(const float4*)&g[c0], gg1 = *(const float4*)&g[c1];
  const float4 bb0 = *(const float4*)&bet[c0], bb1 = *(const float4*)&bet[c1];
  float4 o0, o1;
#pragma unroll
  for (int j = 0; j < 4; ++j) {
    (&o0.x)[j] = fadd32(fmul32(fdiv32((&d0.x)[j], sdev), (&gg0.x)[j]), (&bb0.x)[j]);
    (&o1.x)[j] = fadd32(fmul32(fdiv32((&d1.x)[j], sdev), (&gg1.x)[j]), (&bb1.x)[j]);
  }
  *(float4*)&O[row + c0] = o0;
  *(float4*)&O[row + c1] = o1;
}

// ---- fused residual + LN + pool4 (sub stage; sub never materialized) -------
__global__ __launch_bounds__(256) void k_add_ln_pool(
    const float* __restrict__ A, const float* __restrict__ F,
    const float* __restrict__ g, const float* __restrict__ bet,
    float* __restrict__ OUT) {
  __shared__ float zb[4][512];
  __shared__ float lnr[4][512];
  const int w = threadIdx.x >> 6;
  const int lane = threadIdx.x & 63;
  const int wid = blockIdx.x * 4 + w;
  const size_t row = (size_t)wid * 512;
  const int c0 = lane * 4, c1 = 256 + lane * 4;
  const float4 a0 = *(const float4*)&A[row + c0];
  const float4 a1 = *(const float4*)&A[row + c1];
  const float4 f0 = *(const float4*)&F[row + c0];
  const float4 f1 = *(const float4*)&F[row + c1];
  float4 z0, z1;
#pragma unroll
  for (int j = 0; j < 4; ++j) {
    (&z0.x)[j] = fadd32((&a0.x)[j], (&f0.x)[j]);
    (&z1.x)[j] = fadd32((&a1.x)[j], (&f1.x)[j]);
  }
  *(float4*)&zb[w][c0] = z0;
  *(float4*)&zb[w][c1] = z1;
  const float m = fmul32(np_pairwise512(zb[w], lane), 1.f / 512.f);
  float4 d0, d1, q0, q1;
#pragma unroll
  for (int j = 0; j < 4; ++j) {
    (&d0.x)[j] = fsub32((&z0.x)[j], m);
    (&d1.x)[j] = fsub32((&z1.x)[j], m);
    (&q0.x)[j] = fmul32((&d0.x)[j], (&d0.x)[j]);
    (&q1.x)[j] = fmul32((&d1.x)[j], (&d1.x)[j]);
  }
  *(float4*)&zb[w][c0] = q0;
  *(float4*)&zb[w][c1] = q1;
  const float var = fmul32(np_pairwise512(zb[w], lane), 1.f / 512.f);
  const float sdev = __fsqrt_rn(fadd32(var, 1e-5f));
  float4 o0, o1;
#pragma unroll
  for (int j = 0; j < 4; ++j) {
    (&o0.x)[j] = fadd32(fmul32(fdiv32((&d0.x)[j], sdev), g[c0 + j]), bet[c0 + j]);
    (&o1.x)[j] = fadd32(fmul32(fdiv32((&d1.x)[j], sdev), g[c1 + j]), bet[c1 + j]);
  }
  *(float4*)&lnr[w][c0] = o0;
  *(float4*)&lnr[w][c1] = o1;
  __syncthreads();
  if (threadIdx.x < 128) {
    const int c4 = threadIdx.x * 4;
    const float4 l0 = *(const float4*)&lnr[0][c4];
    const float4 l1 = *(const float4*)&lnr[1][c4];
    const float4 l2 = *(const float4*)&lnr[2][c4];
    const float4 l3 = *(const float4*)&lnr[3][c4];
    float4 o;
#pragma unroll
    for (int j = 0; j < 4; ++j) {
      const float s = fadd32(fadd32(fadd32((&l0.x)[j], (&l1.x)[j]), (&l2.x)[j]),
                             (&l3.x)[j]);
      (&o.x)[j] = fmul32(s, 0.25f);
    }
    *(float4*)&OUT[(size_t)blockIdx.x * 512 + c4] = o;
  }
}

// ---------------- transpose node weights: nwT[n][d][e] = nw[n][e][d] --------
__global__ __launch_bounds__(256) void k_transpose_nw(
    const float* __restrict__ nw, float* __restrict__ nwT) {
  const int idx = blockIdx.x * 256 + threadIdx.x;
  if (idx >= 15 * 4096) return;
  const int n = idx >> 12;
  const int e = (idx >> 6) & 63;
  const int d = idx & 63;
  nwT[(n << 12) + (d << 6) + e] = nw[idx];
}

// numpy einsum baseline-SSE model (bit-frozen).
#define NP_EINSUM64(inp, wp, out_)                                          \
  {                                                                         \
    float c0 = 0.f, c1 = 0.f, c2 = 0.f, c3 = 0.f;                           \
    _Pragma("unroll")                                                       \
    for (int q_ = 0; q_ < 4; ++q_) {                                        \
      const int b_ = 16 * q_;                                               \
      _Pragma("unroll")                                                     \
      for (int u_ = 3; u_ >= 0; --u_) {                                     \
        const int d0_ = b_ + 4 * u_;                                        \
        c0 = fadd32(fmul32(__shfl(inp, d0_ + 0), wp[(d0_ + 0) << 6]), c0);  \
        c1 = fadd32(fmul32(__shfl(inp, d0_ + 1), wp[(d0_ + 1) << 6]), c1);  \
        c2 = fadd32(fmul32(__shfl(inp, d0_ + 2), wp[(d0_ + 2) << 6]), c2);  \
        c3 = fadd32(fmul32(__shfl(inp, d0_ + 3), wp[(d0_ + 3) << 6]), c3);  \
      }                                                                     \
    }                                                                       \
    out_ = fadd32(fadd32(c0, c1), fadd32(c2, c3));                          \
  }

// ---------------- fused spiking tree (bit-frozen) ----------------
__global__ __launch_bounds__(256) void k_tree(
    const float* __restrict__ QKV, const float* __restrict__ nwT,
    const float* __restrict__ nb, const float* __restrict__ th,
    const float* __restrict__ tau, const float* __restrict__ vr,
    float* __restrict__ TK, float* __restrict__ TV) {
  __shared__ float st0[8][8][64];
  __shared__ float st1[4][8][64];
  __shared__ float st2[2][8][64];
  __shared__ float st3[8][64];
  __shared__ float outA[8][8][64];
  __shared__ float outB[4][8][64];
  const int tid = threadIdx.x, w = tid >> 6, lane = tid & 63;
  const int sq = blockIdx.x & 3, bh = blockIdx.x >> 2;
  const int b = bh >> 3, h = bh & 7;
  for (int pass = 0; pass < 2; ++pass) {
    const int koff = 512 + pass * 512;
    for (int r = w; r < 64; r += 4) {
      const int n = r >> 3, sl = r & 7, sg = sq * 8 + sl;
      const float inp = QKV[((size_t)(b * 512 + n * 32 + sg)) * 1536 + koff + h * 64 + lane];
      const int node = 7 + n, pc = node * 64 + lane;
      const float* wp = nwT + node * 4096 + lane;
      float tot;
      NP_EINSUM64(inp, wp, tot);
      const float proj = fadd32(tot, nb[pc]);
      const float v = pass ? fadd32(fmul32(tau[pc], st0[n][sl][lane]), proj) : proj;
      const bool sp = v >= th[pc];
      if (!pass) st0[n][sl][lane] = sp ? vr[pc] : v;
      outA[n][sl][lane] = sp ? proj : 0.f;
    }
    __syncthreads();
    for (int r = w; r < 32; r += 4) {
      const int n = r >> 3, sl = r & 7;
      const float inp = fmul32(0.5f, fadd32(outA[2 * n][sl][lane], outA[2 * n + 1][sl][lane]));
      const int node = 3 + n, pc = node * 64 + lane;
      const float* wp = nwT + node * 4096 + lane;
      float tot;
      NP_EINSUM64(inp, wp, tot);
      const float proj = fadd32(tot, nb[pc]);
      const float v = pass ? fadd32(fmul32(tau[pc], st1[n][sl][lane]), proj) : proj;
      const bool sp = v >= th[pc];
      if (!pass) st1[n][sl][lane] = sp ? vr[pc] : v;
      outB[n][sl][lane] = sp ? proj : 0.f;
    }
    __syncthreads();
    for (int r = w; r < 16; r += 4) {
      const int n = r >> 3, sl = r & 7;
      const float inp = fmul32(0.5f, fadd32(outB[2 * n][sl][lane], outB[2 * n + 1][sl][lane]));
      const int node = 1 + n, pc = node * 64 + lane;
      const float* wp = nwT + node * 4096 + lane;
      float tot;
      NP_EINSUM64(inp, wp, tot);
      const float proj = fadd32(tot, nb[pc]);
      const float v = pass ? fadd32(fmul32(tau[pc], st2[n][sl][lane]), proj) : proj;
      const bool sp = v >= th[pc];
      if (!pass) st2[n][sl][lane] = sp ? vr[pc] : v;
      outA[n][sl][lane] = sp ? proj : 0.f;
    }
    __syncthreads();
    for (int r = w; r < 8; r += 4) {
      const int sl = r & 7, sg = sq * 8 + sl;
      const float inp = fmul32(0.5f, fadd32(outA[0][sl][lane], outA[1][sl][lane]));
      const int pc = lane;
      const float* wp = nwT + lane;
      float tot;
      NP_EINSUM64(inp, wp, tot);
      const float proj = fadd32(tot, nb[pc]);
      const float v = pass ? fadd32(fmul32(tau[pc], st3[sl][lane]), proj) : proj;
      const bool sp = v >= th[pc];
      if (!pass) st3[sl][lane] = sp ? vr[pc] : v;
      float* dst = pass ? TV : TK;
      dst[((size_t)bh * 32 + sg) * 64 + lane] = sp ? proj : 0.f;
    }
    __syncthreads();
  }
}

// ---------------- attention (post-gate, relaxed; fp32 chains) ----------------
__global__ __launch_bounds__(256) void k_attn(
    const float* __restrict__ qkv, const float* __restrict__ treeK,
    const float* __restrict__ treeV, float* __restrict__ attn) {
  __shared__ float Ks[32][65];
  __shared__ float Vs[32][64];
  __shared__ float qs[4][64];
  const int tid = threadIdx.x;
  const int bh = blockIdx.x >> 7;
  const int lq0 = (blockIdx.x & 127) * 4;
  const int b = bh >> 3, h = bh & 7;
  for (int i = tid; i < 2048; i += 256) {
    const int j = i >> 6, d = i & 63;
    Ks[j][d] = treeK[((size_t)bh * 32 + j) * 64 + d];
    Vs[j][d] = treeV[((size_t)bh * 32 + j) * 64 + d];
  }
  {
    const int w = tid >> 6, d = tid & 63;
    qs[w][d] = qkv[((size_t)(b * 512) + lq0 + w) * 1536 + h * 64 + d];
  }
  __syncthreads();
  const int w = tid >> 6;
  const int lane = tid & 63;
  const int j = lane & 31;
  float sc = 0.f;
#pragma unroll
  for (int d = 0; d < 64; ++d) sc = __fmaf_rn(qs[w][d], Ks[j][d], sc);
  sc = fmul32(sc, 0.125f);
  float m = sc;
#pragma unroll
  for (int k = 1; k < 32; k <<= 1) m = fmaxf(m, __shfl_xor(m, k));
  float p = expf(fsub32(sc, m));
  float sum = p;
#pragma unroll
  for (int k = 1; k < 32; k <<= 1) sum += __shfl_xor(sum, k);
  p = fdiv32(p, sum);
  float acc = 0.f;
#pragma unroll
  for (int jj = 0; jj < 32; ++jj)
    acc = __fmaf_rn(__shfl(p, jj), Vs[jj][lane], acc);
  attn[((size_t)(b * 512) + lq0 + w) * 512 + h * 64 + lane] = acc;
}

// ---------------- linear interpolation 512 -> 4096 rows ----------------
__global__ __launch_bounds__(256) void k_interp(
    const float* __restrict__ rows, float* __restrict__ out) {
  const int wid = blockIdx.x * 4 + (threadIdx.x >> 6);  // b*4096+s
  const int lane = threadIdx.x & 63;
  const int b = wid >> 12;
  const int s = wid & 4095;
  const double src = fmax(((double)s + 0.5) * 0.125 - 0.5, 0.0);
  const int i0 = (int)src;
  const int i1 = min(i0 + 1, 511);
  const double w1 = src - (double)i0;
  const double w0 = 1.0 - w1;
  const size_t r0 = ((size_t)b * 512 + i0) * 512;
  const size_t r1 = ((size_t)b * 512 + i1) * 512;
  const size_t o = (size_t)wid * 512;
#pragma unroll
  for (int k = 0; k < 2; ++k) {
    const int c4 = lane + 64 * k;
    const float4 a = *reinterpret_cast<const float4*>(&rows[r0 + (size_t)c4 * 4]);
    const float4 c = *reinterpret_cast<const float4*>(&rows[r1 + (size_t)c4 * 4]);
    float4 r;
    r.x = (float)((double)a.x * w0 + (double)c.x * w1);
    r.y = (float)((double)a.y * w0 + (double)c.y * w1);
    r.z = (float)((double)a.z * w0 + (double)c.z * w1);
    r.w = (float)((double)a.w * w0 + (double)c.w * w1);
    *reinterpret_cast<float4*>(&out[o + (size_t)c4 * 4]) = r;
  }
}

extern "C" void kernel_launch(void* const* d_in, const int* in_sizes, int n_in,
                              void* d_out, int out_size, void* d_ws, size_t ws_size,
                              hipStream_t stream) {
  const int*   text    = (const int*)d_in[0];
  const float* pe      = (const float*)d_in[1];
  const float* id_w    = (const float*)d_in[2];
  const float* id_b    = (const float*)d_in[3];
  const float* eg      = (const float*)d_in[4];
  const float* ebeta   = (const float*)d_in[5];
  const float* sub_w   = (const float*)d_in[6];
  const float* sub_b   = (const float*)d_in[7];
  const float* sub_th  = (const float*)d_in[8];
  const float* sub_ng  = (const float*)d_in[11];
  const float* sub_nb  = (const float*)d_in[12];
  const float* word_w  = (const float*)d_in[13];
  const float* word_b  = (const float*)d_in[14];
  const float* word_th = (const float*)d_in[15];
  const float* word_ng = (const float*)d_in[18];
  const float* word_nb = (const float*)d_in[19];
  const float* qkv_w   = (const float*)d_in[20];
  const float* qkv_b   = (const float*)d_in[21];
  const float* node_w  = (const float*)d_in[22];
  const float* node_b  = (const float*)d_in[23];
  const float* node_th = (const float*)d_in[24];
  const float* node_tau= (const float*)d_in[25];
  const float* node_vr = (const float*)d_in[26];
  const float* out_ng  = (const float*)d_in[27];
  const float* out_nb  = (const float*)d_in[28];

  float* O   = (float*)d_out;   // 67,108,864 floats
  float* WSF = (float*)d_ws;

  // d_out regions (floats)
  float* FU  = O;               // fused1 [0 : 33554432)
  float* GZ1 = O + 33554432;    // sub gated proj [33554432 : 67108864)
  float* WD  = O + 33554432;    // word [33554432 : 41943040)
  float* GZ2 = O + 41943040;    // word gated proj (dead before qkv write)
  float* QKV = O + 41943040;    // qkv  [41943040 : 67108864)

  // ws regions (floats)
  float* W1   = WSF;            // [0 : 8388608)
  float* NWT  = WSF + 8388608;  // 61440
  float* TK   = WSF + 8450048;  // 524288
  float* TV   = WSF + 8974336;  // 524288
  float* ROWS = WSF + 9498624;  // 8388608
  float* WTs  = WSF + 17887232; // 262144  (sub_w^T  [512][512])
  float* WTw  = WSF + 18149376; // 262144  (word_w^T [512][512])
  float* WTq  = WSF + 18411520; // 786432  (qkv_w^T  [512][1536])
  float* ATT  = WSF;            // reuses W1 (dead after word LN)

  // 0. weight transposes (independent of activations)
  k_transpose_w<<<dim3(16, 16), 256, 0, stream>>>(sub_w, WTs, 512);
  k_transpose_w<<<dim3(16, 16), 256, 0, stream>>>(word_w, WTw, 512);
  k_transpose_w<<<dim3(48, 16), 256, 0, stream>>>(qkv_w, WTq, 1536);
  k_transpose_nw<<<240, 256, 0, stream>>>(node_w, NWT);
  // 1. embed + LN + pool2 -> FU
  k_embed<<<16384, 256, 0, stream>>>(text, pe, id_w, id_b, eg, ebeta, FU);
  // 2. GZ1 = gate(FU @ sub_w^T + b)
  k_gemm_nt<<<dim3(1024, 2), 512, 0, stream>>>(FU, WTs, sub_b, sub_th, GZ1, 512);
  // 3. W1 = pool4(LN(GZ1 + FU))  — sub never materialized
  k_add_ln_pool<<<16384, 256, 0, stream>>>(GZ1, FU, sub_ng, sub_nb, W1);
  // 4. GZ2 = gate(W1 @ word_w^T + b)
  k_gemm_nt<<<dim3(256, 2), 512, 0, stream>>>(W1, WTw, word_b, word_th, GZ2, 512);
  // 5. word = LN(GZ2 + W1) -> WD
  k_add_ln<<<4096, 256, 0, stream>>>(GZ2, W1, word_ng, word_nb, WD, 16384);
  // 6. QKV = WD @ qkv_w^T + b
  k_gemm_nt<<<dim3(256, 6), 512, 0, stream>>>(WD, WTq, qkv_b, nullptr, QKV, 1536);
  // 7. fused spiking tree -> TK, TV
  k_tree<<<1024, 256, 0, stream>>>(QKV, NWT, node_b, node_th,
                                   node_tau, node_vr, TK, TV);
  // 8. attention -> ATT (reuses dead W1 space)
  k_attn<<<32768, 256, 0, stream>>>(QKV, TK, TV, ATT);
  // 9. rows = LN(ATT + word) -> ROWS
  k_add_ln<<<4096, 256, 0, stream>>>(ATT, WD, out_ng, out_nb, ROWS, 16384);
  // 10. interpolate 512 -> 4096 rows, full fp32 d_out overwrite
  k_interp<<<32768, 256, 0, stream>>>(ROWS, O);
}

// Round 19
// 1635.893 us; speedup vs baseline: 6.0007x; 1.0750x over previous
//
#include <hip/hip_runtime.h>
#include <math.h>

// ---------------------------------------------------------------------------
// TreeTextEmbed — numpy-faithful fp32 pipeline, round 19.
// NUMERICS FROZEN (r7-r18 passed, absmax 0.015625): ascending-k fp32 FMA chain
// w/ 384/128 panels; AVX512 pairwise mean; baseline-SSE einsum; __f*_rn
// elementwise in np op order.
// PERF vs r18 (Occupancy stuck at 23% = 1 block/CU across r11-r18; 42% of
// GEMM cycles are barrier-drain idle with no co-resident block to cover):
//   - SINGLE CHANGE: k_gemm_nt __launch_bounds__(512, 4) -> request 4
//     waves/EU = 2 blocks/CU (VGPR 84 <= 128 tier, LDS 2x64KB <= 160KB fit).
// ---------------------------------------------------------------------------

typedef float f32x2 __attribute__((ext_vector_type(2)));

__device__ __forceinline__ float fadd32(float a, float b) { return __fadd_rn(a, b); }
__device__ __forceinline__ float fmul32(float a, float b) { return __fmul_rn(a, b); }
__device__ __forceinline__ float fsub32(float a, float b) { return __fsub_rn(a, b); }
__device__ __forceinline__ float fdiv32(float a, float b) { return __fdiv_rn(a, b); }

// packed fp32 FMA: d = a*b + d (two independent IEEE RN fp32 ops)
__device__ __forceinline__ void pkfma(f32x2& d, f32x2 a, f32x2 b) {
  asm("v_pk_fma_f32 %0, %1, %2, %0" : "+v"(d) : "v"(a), "v"(b));
}

// async global->LDS, 16B per lane; LDS dest = wave-uniform base + lane*16
__device__ __forceinline__ void gload16(const float* g, float* l) {
  __builtin_amdgcn_global_load_lds(
      (const __attribute__((address_space(1))) void*)g,
      (__attribute__((address_space(3))) void*)l, 16, 0, 0);
}

// numpy pairwise sum of contiguous 512 floats, AVX512 model (bit-frozen).
__device__ __forceinline__ float np_pairwise512(const float* row, int lane) {
  const int L = lane >> 4, j = lane & 15;
  const float* p = row + 128 * L + j;
  const float r0 = p[0],  r1 = p[16], r2 = p[32],  r3 = p[48];
  const float r4 = p[64], r5 = p[80], r6 = p[96],  r7 = p[112];
  float v = fadd32(fadd32(fadd32(r0, r1), fadd32(r2, r3)),
                   fadd32(fadd32(r4, r5), fadd32(r6, r7)));
  v = fadd32(v, __shfl_xor(v, 8));
  v = fadd32(v, __shfl_xor(v, 4));
  v = fadd32(v, __shfl_xor(v, 2));
  v = fadd32(v, __shfl_xor(v, 1));
  v = fadd32(v, __shfl_xor(v, 16));
  v = fadd32(v, __shfl_xor(v, 32));
  return v;
}

// ---------------- K1: embed + LN + pool2 (float4; per-element ops frozen) ----
__global__ __launch_bounds__(256) void k_embed(
    const int* __restrict__ text, const float* __restrict__ pe,
    const float* __restrict__ id_w, const float* __restrict__ id_b,
    const float* __restrict__ eg, const float* __restrict__ eb,
    float* __restrict__ fused) {
  __shared__ float rb[4][512];
  const int w = threadIdx.x >> 6;
  const int lane = threadIdx.x & 63;
  const int wid = blockIdx.x * 4 + w;  // row b*2048+t
  const int b = wid >> 11;
  const int t = wid & 2047;
  const int c0 = lane * 4, c1 = 256 + lane * 4;
  const float4 iw0 = *(const float4*)&id_w[c0], iw1 = *(const float4*)&id_w[c1];
  const float4 ib0 = *(const float4*)&id_b[c0], ib1 = *(const float4*)&id_b[c1];
  const float4 g0  = *(const float4*)&eg[c0],  g1  = *(const float4*)&eg[c1];
  const float4 e0  = *(const float4*)&eb[c0],  e1  = *(const float4*)&eb[c1];
  float4 fus0, fus1;
#pragma unroll
  for (int ss = 0; ss < 2; ++ss) {
    const int s = 2 * t + ss;
    const float idv = (float)text[b * 4096 + s];
    const float4 p0 = *(const float4*)&pe[(size_t)s * 512 + c0];
    const float4 p1 = *(const float4*)&pe[(size_t)s * 512 + c1];
    float4 x0, x1;
#pragma unroll
    for (int j = 0; j < 4; ++j) {
      (&x0.x)[j] = fadd32(fadd32(fmul32(idv, (&iw0.x)[j]), (&ib0.x)[j]), (&p0.x)[j]);
      (&x1.x)[j] = fadd32(fadd32(fmul32(idv, (&iw1.x)[j]), (&ib1.x)[j]), (&p1.x)[j]);
    }
    *(float4*)&rb[w][c0] = x0;
    *(float4*)&rb[w][c1] = x1;
    const float m = fmul32(np_pairwise512(rb[w], lane), 1.f / 512.f);
    float4 d0, d1, q0, q1;
#pragma unroll
    for (int j = 0; j < 4; ++j) {
      (&d0.x)[j] = fsub32((&x0.x)[j], m);
      (&d1.x)[j] = fsub32((&x1.x)[j], m);
      (&q0.x)[j] = fmul32((&d0.x)[j], (&d0.x)[j]);
      (&q1.x)[j] = fmul32((&d1.x)[j], (&d1.x)[j]);
    }
    *(float4*)&rb[w][c0] = q0;
    *(float4*)&rb[w][c1] = q1;
    const float var = fmul32(np_pairwise512(rb[w], lane), 1.f / 512.f);
    const float sdev = __fsqrt_rn(fadd32(var, 1e-5f));
#pragma unroll
    for (int j = 0; j < 4; ++j) {
      const float l0 = fadd32(fmul32(fdiv32((&d0.x)[j], sdev), (&g0.x)[j]), (&e0.x)[j]);
      const float l1 = fadd32(fmul32(fdiv32((&d1.x)[j], sdev), (&g1.x)[j]), (&e1.x)[j]);
      if (ss) {
        (&fus0.x)[j] = fmul32(fadd32((&fus0.x)[j], l0), 0.5f);
        (&fus1.x)[j] = fmul32(fadd32((&fus1.x)[j], l1), 0.5f);
      } else {
        (&fus0.x)[j] = l0;
        (&fus1.x)[j] = l1;
      }
    }
  }
  const size_t row = (size_t)wid * 512;
  *(float4*)&fused[row + c0] = fus0;
  *(float4*)&fused[row + c1] = fus1;
}

// ---------------- tiled weight transpose: WT[k][n] = W[n][k], K=512 ----------
__global__ __launch_bounds__(256) void k_transpose_w(
    const float* __restrict__ W, float* __restrict__ WT, int Nn) {
  __shared__ float t[32][33];
  const int n0 = blockIdx.x * 32, k0 = blockIdx.y * 32;
  const int li = threadIdx.x & 31, wi = threadIdx.x >> 5;
  for (int r = wi; r < 32; r += 8)
    t[r][li] = W[(size_t)(n0 + r) * 512 + k0 + li];
  __syncthreads();
  for (int r = wi; r < 32; r += 8)
    WT[(size_t)(k0 + r) * Nn + n0 + li] = t[li][r];
}

// ---- unified np-sgemm from WT[K][N]: OUT = [gate](X @ W^T + bias)
// BM=64, BN=256, BK=32; 512 thr (8 waves); per-thread 4 rows x 8 cols
// (4 col-PAIRS via v_pk_fma_f32). W in LDS (dbuf, gload_lds); X direct
// from global/L2. One __syncthreads per tile. 2 blocks/CU requested.
// Chain per element: k ascending, panels [0,384)+[384,512)  (bit-frozen).
#define GEMM_INNER(acc, buf, kbase)                                  \
  _Pragma("unroll")                                                  \
  for (int kq = 0; kq < 32; kq += 4) {                               \
    float4 xf[4];                                                    \
    _Pragma("unroll")                                                \
    for (int r = 0; r < 4; ++r)                                      \
      xf[r] = *(const float4*)&X[(bm + rg * 4 + r) * 512 + (kbase) + kq]; \
    _Pragma("unroll")                                                \
    for (int u = 0; u < 4; ++u) {                                    \
      const float4 w0 = *(const float4*)&Ws[buf][kq + u][cg * 4];    \
      const float4 w1 = *(const float4*)&Ws[buf][kq + u][128 + cg * 4]; \
      const f32x2 wp0 = {w0.x, w0.y}, wp1 = {w0.z, w0.w};            \
      const f32x2 wp2 = {w1.x, w1.y}, wp3 = {w1.z, w1.w};            \
      _Pragma("unroll")                                              \
      for (int r = 0; r < 4; ++r) {                                  \
        const float xv = (&xf[r].x)[u];                              \
        const f32x2 xv2 = {xv, xv};                                  \
        pkfma(acc[r][0], xv2, wp0);                                  \
        pkfma(acc[r][1], xv2, wp1);                                  \
        pkfma(acc[r][2], xv2, wp2);                                  \
        pkfma(acc[r][3], xv2, wp3);                                  \
      }                                                              \
    }                                                                \
  }

// stage one 32x256 W tile into buf: 4 gload16 per wave
#define STAGE(buf, k0)                                                        \
  {                                                                           \
    _Pragma("unroll")                                                         \
    for (int c = 0; c < 4; ++c)                                               \
      gload16(&WT[(size_t)((k0) + wvid * 4 + c) * N + bn + lane * 4],         \
              &Ws[buf][wvid * 4 + c][0]);                                     \
  }

__global__ __launch_bounds__(512, 4) void k_gemm_nt(
    const float* __restrict__ X, const float* __restrict__ WT,
    const float* __restrict__ bias, const float* __restrict__ th,
    float* __restrict__ OUT, int N) {
  __shared__ float Ws[2][32][256];   // 64 KB — linear for gload_lds (W only)
  const int tid = threadIdx.x;
  const int wvid = tid >> 6, lane = tid & 63;
  const int rg = tid >> 5;   // 0..15 (row group, 4 rows each)
  const int cg = tid & 31;   // 0..31 (col group, 2x4 cols each)
  const size_t bm = (size_t)blockIdx.x * 64;
  const int bn = blockIdx.y * 256;

  f32x2 accA[4][4], accB[4][4];
#pragma unroll
  for (int r = 0; r < 4; ++r)
#pragma unroll
    for (int c = 0; c < 4; ++c) {
      accA[r][c] = (f32x2){0.f, 0.f};
      accB[r][c] = (f32x2){0.f, 0.f};
    }

  STAGE(0, 0);
  __syncthreads();
  for (int t = 0; t < 16; ++t) {
    const int cur = t & 1;
    if (t < 15) STAGE(cur ^ 1, (t + 1) * 32);
    if (t < 12) { GEMM_INNER(accA, cur, t * 32); }
    else        { GEMM_INNER(accB, cur, t * 32); }
    __syncthreads();
  }
  // epilogue: C = P1+P2; +bias; optional gate (bit-frozen sequence)
#pragma unroll
  for (int r = 0; r < 4; ++r) {
    const size_t rb = (bm + rg * 4 + r) * (size_t)N;
    float a8[8] = {accA[r][0].x, accA[r][0].y, accA[r][1].x, accA[r][1].y,
                   accA[r][2].x, accA[r][2].y, accA[r][3].x, accA[r][3].y};
    float b8[8] = {accB[r][0].x, accB[r][0].y, accB[r][1].x, accB[r][1].y,
                   accB[r][2].x, accB[r][2].y, accB[r][3].x, accB[r][3].y};
    float4 o0, o1;
#pragma unroll
    for (int c = 0; c < 4; ++c) {
      const int col0 = bn + cg * 4 + c;
      const int col1 = bn + 128 + cg * 4 + c;
      const float v0 = fadd32(fadd32(a8[c], b8[c]), bias[col0]);
      const float v1 = fadd32(fadd32(a8[4 + c], b8[4 + c]), bias[col1]);
      (&o0.x)[c] = th ? ((v0 >= th[col0]) ? v0 : 0.f) : v0;
      (&o1.x)[c] = th ? ((v1 >= th[col1]) ? v1 : 0.f) : v1;
    }
    *(float4*)&OUT[rb + bn + cg * 4] = o0;
    *(float4*)&OUT[rb + bn + 128 + cg * 4] = o1;
  }
}

// ---------------- residual + LN (float4; per-element ops frozen) ------------
__global__ __launch_bounds__(256) void k_add_ln(
    const float* __restrict__ A, const float* F,
    const float* __restrict__ g, const float* __restrict__ bet,
    float* O, int nrows) {
  __shared__ float zb[4][512];
  const int w = threadIdx.x >> 6;
  const int lane = threadIdx.x & 63;
  const int wid = blockIdx.x * 4 + w;
  if (wid >= nrows) return;
  const size_t row = (size_t)wid * 512;
  const int c0 = lane * 4, c1 = 256 + lane * 4;
  const float4 a0 = *(const float4*)&A[row + c0];
  const float4 a1 = *(const float4*)&A[row + c1];
  const float4 f0 = *(const float4*)&F[row + c0];
  const float4 f1 = *(const float4*)&F[row + c1];
  float4 z0, z1;
#pragma unroll
  for (int j = 0; j < 4; ++j) {
    (&z0.x)[j] = fadd32((&a0.x)[j], (&f0.x)[j]);
    (&z1.x)[j] = fadd32((&a1.x)[j], (&f1.x)[j]);
  }
  *(float4*)&zb[w][c0] = z0;
  *(float4*)&zb[w][c1] = z1;
  const float m = fmul32(np_pairwise512(zb[w], lane), 1.f / 512.f);
  float4 d0, d1, q0, q1;
#pragma unroll
  for (int j = 0; j < 4; ++j) {
    (&d0.x)[j] = fsub32((&z0.x)[j], m);
    (&d1.x)[j] = fsub32((&z1.x)[j], m);
    (&q0.x)[j] = fmul32((&d0.x)[j], (&d0.x)[j]);
    (&q1.x)[j] = fmul32((&d1.x)[j], (&d1.x)[j]);
  }
  *(float4*)&zb[w][c0] = q0;
  *(float4*)&zb[w][c1] = q1;
  const float var = fmul32(np_pairwise512(zb[w], lane), 1.f / 512.f);
  const float sdev = __fsqrt_rn(fadd32(var, 1e-5f));
  const float4 gg0 = *(const float4*)&g[c0], gg1 = *(const float4*)&g[c1];
  const float4 bb0 = *(const float4*)&bet[c0], bb1 = *(const float4*)&bet[c1];
  float4 o0, o1;
#pragma unroll
  for (int j = 0; j < 4; ++j) {
    (&o0.x)[j] = fadd32(fmul32(fdiv32((&d0.x)[j], sdev), (&gg0.x)[j]), (&bb0.x)[j]);
    (&o1.x)[j] = fadd32(fmul32(fdiv32((&d1.x)[j], sdev), (&gg1.x)[j]), (&bb1.x)[j]);
  }
  *(float4*)&O[row + c0] = o0;
  *(float4*)&O[row + c1] = o1;
}

// ---- fused residual + LN + pool4 (sub stage; sub never materialized) -------
__global__ __launch_bounds__(256) void k_add_ln_pool(
    const float* __restrict__ A, const float* __restrict__ F,
    const float* __restrict__ g, const float* __restrict__ bet,
    float* __restrict__ OUT) {
  __shared__ float zb[4][512];
  __shared__ float lnr[4][512];
  const int w = threadIdx.x >> 6;
  const int lane = threadIdx.x & 63;
  const int wid = blockIdx.x * 4 + w;
  const size_t row = (size_t)wid * 512;
  const int c0 = lane * 4, c1 = 256 + lane * 4;
  const float4 a0 = *(const float4*)&A[row + c0];
  const float4 a1 = *(const float4*)&A[row + c1];
  const float4 f0 = *(const float4*)&F[row + c0];
  const float4 f1 = *(const float4*)&F[row + c1];
  float4 z0, z1;
#pragma unroll
  for (int j = 0; j < 4; ++j) {
    (&z0.x)[j] = fadd32((&a0.x)[j], (&f0.x)[j]);
    (&z1.x)[j] = fadd32((&a1.x)[j], (&f1.x)[j]);
  }
  *(float4*)&zb[w][c0] = z0;
  *(float4*)&zb[w][c1] = z1;
  const float m = fmul32(np_pairwise512(zb[w], lane), 1.f / 512.f);
  float4 d0, d1, q0, q1;
#pragma unroll
  for (int j = 0; j < 4; ++j) {
    (&d0.x)[j] = fsub32((&z0.x)[j], m);
    (&d1.x)[j] = fsub32((&z1.x)[j], m);
    (&q0.x)[j] = fmul32((&d0.x)[j], (&d0.x)[j]);
    (&q1.x)[j] = fmul32((&d1.x)[j], (&d1.x)[j]);
  }
  *(float4*)&zb[w][c0] = q0;
  *(float4*)&zb[w][c1] = q1;
  const float var = fmul32(np_pairwise512(zb[w], lane), 1.f / 512.f);
  const float sdev = __fsqrt_rn(fadd32(var, 1e-5f));
  float4 o0, o1;
#pragma unroll
  for (int j = 0; j < 4; ++j) {
    (&o0.x)[j] = fadd32(fmul32(fdiv32((&d0.x)[j], sdev), g[c0 + j]), bet[c0 + j]);
    (&o1.x)[j] = fadd32(fmul32(fdiv32((&d1.x)[j], sdev), g[c1 + j]), bet[c1 + j]);
  }
  *(float4*)&lnr[w][c0] = o0;
  *(float4*)&lnr[w][c1] = o1;
  __syncthreads();
  if (threadIdx.x < 128) {
    const int c4 = threadIdx.x * 4;
    const float4 l0 = *(const float4*)&lnr[0][c4];
    const float4 l1 = *(const float4*)&lnr[1][c4];
    const float4 l2 = *(const float4*)&lnr[2][c4];
    const float4 l3 = *(const float4*)&lnr[3][c4];
    float4 o;
#pragma unroll
    for (int j = 0; j < 4; ++j) {
      const float s = fadd32(fadd32(fadd32((&l0.x)[j], (&l1.x)[j]), (&l2.x)[j]),
                             (&l3.x)[j]);
      (&o.x)[j] = fmul32(s, 0.25f);
    }
    *(float4*)&OUT[(size_t)blockIdx.x * 512 + c4] = o;
  }
}

// ---------------- transpose node weights: nwT[n][d][e] = nw[n][e][d] --------
__global__ __launch_bounds__(256) void k_transpose_nw(
    const float* __restrict__ nw, float* __restrict__ nwT) {
  const int idx = blockIdx.x * 256 + threadIdx.x;
  if (idx >= 15 * 4096) return;
  const int n = idx >> 12;
  const int e = (idx >> 6) & 63;
  const int d = idx & 63;
  nwT[(n << 12) + (d << 6) + e] = nw[idx];
}

// numpy einsum baseline-SSE model (bit-frozen).
#define NP_EINSUM64(inp, wp, out_)                                          \
  {                                                                         \
    float c0 = 0.f, c1 = 0.f, c2 = 0.f, c3 = 0.f;                           \
    _Pragma("unroll")                                                       \
    for (int q_ = 0; q_ < 4; ++q_) {                                        \
      const int b_ = 16 * q_;                                               \
      _Pragma("unroll")                                                     \
      for (int u_ = 3; u_ >= 0; --u_) {                                     \
        const int d0_ = b_ + 4 * u_;                                        \
        c0 = fadd32(fmul32(__shfl(inp, d0_ + 0), wp[(d0_ + 0) << 6]), c0);  \
        c1 = fadd32(fmul32(__shfl(inp, d0_ + 1), wp[(d0_ + 1) << 6]), c1);  \
        c2 = fadd32(fmul32(__shfl(inp, d0_ + 2), wp[(d0_ + 2) << 6]), c2);  \
        c3 = fadd32(fmul32(__shfl(inp, d0_ + 3), wp[(d0_ + 3) << 6]), c3);  \
      }                                                                     \
    }                                                                       \
    out_ = fadd32(fadd32(c0, c1), fadd32(c2, c3));                          \
  }

// ---------------- fused spiking tree (bit-frozen) ----------------
__global__ __launch_bounds__(256) void k_tree(
    const float* __restrict__ QKV, const float* __restrict__ nwT,
    const float* __restrict__ nb, const float* __restrict__ th,
    const float* __restrict__ tau, const float* __restrict__ vr,
    float* __restrict__ TK, float* __restrict__ TV) {
  __shared__ float st0[8][8][64];
  __shared__ float st1[4][8][64];
  __shared__ float st2[2][8][64];
  __shared__ float st3[8][64];
  __shared__ float outA[8][8][64];
  __shared__ float outB[4][8][64];
  const int tid = threadIdx.x, w = tid >> 6, lane = tid & 63;
  const int sq = blockIdx.x & 3, bh = blockIdx.x >> 2;
  const int b = bh >> 3, h = bh & 7;
  for (int pass = 0; pass < 2; ++pass) {
    const int koff = 512 + pass * 512;
    for (int r = w; r < 64; r += 4) {
      const int n = r >> 3, sl = r & 7, sg = sq * 8 + sl;
      const float inp = QKV[((size_t)(b * 512 + n * 32 + sg)) * 1536 + koff + h * 64 + lane];
      const int node = 7 + n, pc = node * 64 + lane;
      const float* wp = nwT + node * 4096 + lane;
      float tot;
      NP_EINSUM64(inp, wp, tot);
      const float proj = fadd32(tot, nb[pc]);
      const float v = pass ? fadd32(fmul32(tau[pc], st0[n][sl][lane]), proj) : proj;
      const bool sp = v >= th[pc];
      if (!pass) st0[n][sl][lane] = sp ? vr[pc] : v;
      outA[n][sl][lane] = sp ? proj : 0.f;
    }
    __syncthreads();
    for (int r = w; r < 32; r += 4) {
      const int n = r >> 3, sl = r & 7;
      const float inp = fmul32(0.5f, fadd32(outA[2 * n][sl][lane], outA[2 * n + 1][sl][lane]));
      const int node = 3 + n, pc = node * 64 + lane;
      const float* wp = nwT + node * 4096 + lane;
      float tot;
      NP_EINSUM64(inp, wp, tot);
      const float proj = fadd32(tot, nb[pc]);
      const float v = pass ? fadd32(fmul32(tau[pc], st1[n][sl][lane]), proj) : proj;
      const bool sp = v >= th[pc];
      if (!pass) st1[n][sl][lane] = sp ? vr[pc] : v;
      outB[n][sl][lane] = sp ? proj : 0.f;
    }
    __syncthreads();
    for (int r = w; r < 16; r += 4) {
      const int n = r >> 3, sl = r & 7;
      const float inp = fmul32(0.5f, fadd32(outB[2 * n][sl][lane], outB[2 * n + 1][sl][lane]));
      const int node = 1 + n, pc = node * 64 + lane;
      const float* wp = nwT + node * 4096 + lane;
      float tot;
      NP_EINSUM64(inp, wp, tot);
      const float proj = fadd32(tot, nb[pc]);
      const float v = pass ? fadd32(fmul32(tau[pc], st2[n][sl][lane]), proj) : proj;
      const bool sp = v >= th[pc];
      if (!pass) st2[n][sl][lane] = sp ? vr[pc] : v;
      outA[n][sl][lane] = sp ? proj : 0.f;
    }
    __syncthreads();
    for (int r = w; r < 8; r += 4) {
      const int sl = r & 7, sg = sq * 8 + sl;
      const float inp = fmul32(0.5f, fadd32(outA[0][sl][lane], outA[1][sl][lane]));
      const int pc = lane;
      const float* wp = nwT + lane;
      float tot;
      NP_EINSUM64(inp, wp, tot);
      const float proj = fadd32(tot, nb[pc]);
      const float v = pass ? fadd32(fmul32(tau[pc], st3[sl][lane]), proj) : proj;
      const bool sp = v >= th[pc];
      if (!pass) st3[sl][lane] = sp ? vr[pc] : v;
      float* dst = pass ? TV : TK;
      dst[((size_t)bh * 32 + sg) * 64 + lane] = sp ? proj : 0.f;
    }
    __syncthreads();
  }
}

// ---------------- attention (post-gate, relaxed; fp32 chains) ----------------
__global__ __launch_bounds__(256) void k_attn(
    const float* __restrict__ qkv, const float* __restrict__ treeK,
    const float* __restrict__ treeV, float* __restrict__ attn) {
  __shared__ float Ks[32][65];
  __shared__ float Vs[32][64];
  __shared__ float qs[4][64];
  const int tid = threadIdx.x;
  const int bh = blockIdx.x >> 7;
  const int lq0 = (blockIdx.x & 127) * 4;
  const int b = bh >> 3, h = bh & 7;
  for (int i = tid; i < 2048; i += 256) {
    const int j = i >> 6, d = i & 63;
    Ks[j][d] = treeK[((size_t)bh * 32 + j) * 64 + d];
    Vs[j][d] = treeV[((size_t)bh * 32 + j) * 64 + d];
  }
  {
    const int w = tid >> 6, d = tid & 63;
    qs[w][d] = qkv[((size_t)(b * 512) + lq0 + w) * 1536 + h * 64 + d];
  }
  __syncthreads();
  const int w = tid >> 6;
  const int lane = tid & 63;
  const int j = lane & 31;
  float sc = 0.f;
#pragma unroll
  for (int d = 0; d < 64; ++d) sc = __fmaf_rn(qs[w][d], Ks[j][d], sc);
  sc = fmul32(sc, 0.125f);
  float m = sc;
#pragma unroll
  for (int k = 1; k < 32; k <<= 1) m = fmaxf(m, __shfl_xor(m, k));
  float p = expf(fsub32(sc, m));
  float sum = p;
#pragma unroll
  for (int k = 1; k < 32; k <<= 1) sum += __shfl_xor(sum, k);
  p = fdiv32(p, sum);
  float acc = 0.f;
#pragma unroll
  for (int jj = 0; jj < 32; ++jj)
    acc = __fmaf_rn(__shfl(p, jj), Vs[jj][lane], acc);
  attn[((size_t)(b * 512) + lq0 + w) * 512 + h * 64 + lane] = acc;
}

// ---------------- linear interpolation 512 -> 4096 rows ----------------
__global__ __launch_bounds__(256) void k_interp(
    const float* __restrict__ rows, float* __restrict__ out) {
  const int wid = blockIdx.x * 4 + (threadIdx.x >> 6);  // b*4096+s
  const int lane = threadIdx.x & 63;
  const int b = wid >> 12;
  const int s = wid & 4095;
  const double src = fmax(((double)s + 0.5) * 0.125 - 0.5, 0.0);
  const int i0 = (int)src;
  const int i1 = min(i0 + 1, 511);
  const double w1 = src - (double)i0;
  const double w0 = 1.0 - w1;
  const size_t r0 = ((size_t)b * 512 + i0) * 512;
  const size_t r1 = ((size_t)b * 512 + i1) * 512;
  const size_t o = (size_t)wid * 512;
#pragma unroll
  for (int k = 0; k < 2; ++k) {
    const int c4 = lane + 64 * k;
    const float4 a = *reinterpret_cast<const float4*>(&rows[r0 + (size_t)c4 * 4]);
    const float4 c = *reinterpret_cast<const float4*>(&rows[r1 + (size_t)c4 * 4]);
    float4 r;
    r.x = (float)((double)a.x * w0 + (double)c.x * w1);
    r.y = (float)((double)a.y * w0 + (double)c.y * w1);
    r.z = (float)((double)a.z * w0 + (double)c.z * w1);
    r.w = (float)((double)a.w * w0 + (double)c.w * w1);
    *reinterpret_cast<float4*>(&out[o + (size_t)c4 * 4]) = r;
  }
}

extern "C" void kernel_launch(void* const* d_in, const int* in_sizes, int n_in,
                              void* d_out, int out_size, void* d_ws, size_t ws_size,
                              hipStream_t stream) {
  const int*   text    = (const int*)d_in[0];
  const float* pe      = (const float*)d_in[1];
  const float* id_w    = (const float*)d_in[2];
  const float* id_b    = (const float*)d_in[3];
  const float* eg      = (const float*)d_in[4];
  const float* ebeta   = (const float*)d_in[5];
  const float* sub_w   = (const float*)d_in[6];
  const float* sub_b   = (const float*)d_in[7];
  const float* sub_th  = (const float*)d_in[8];
  const float* sub_ng  = (const float*)d_in[11];
  const float* sub_nb  = (const float*)d_in[12];
  const float* word_w  = (const float*)d_in[13];
  const float* word_b  = (const float*)d_in[14];
  const float* word_th = (const float*)d_in[15];
  const float* word_ng = (const float*)d_in[18];
  const float* word_nb = (const float*)d_in[19];
  const float* qkv_w   = (const float*)d_in[20];
  const float* qkv_b   = (const float*)d_in[21];
  const float* node_w  = (const float*)d_in[22];
  const float* node_b  = (const float*)d_in[23];
  const float* node_th = (const float*)d_in[24];
  const float* node_tau= (const float*)d_in[25];
  const float* node_vr = (const float*)d_in[26];
  const float* out_ng  = (const float*)d_in[27];
  const float* out_nb  = (const float*)d_in[28];

  float* O   = (float*)d_out;   // 67,108,864 floats
  float* WSF = (float*)d_ws;

  // d_out regions (floats)
  float* FU  = O;               // fused1 [0 : 33554432)
  float* GZ1 = O + 33554432;    // sub gated proj [33554432 : 67108864)
  float* WD  = O + 33554432;    // word [33554432 : 41943040)
  float* GZ2 = O + 41943040;    // word gated proj (dead before qkv write)
  float* QKV = O + 41943040;    // qkv  [41943040 : 67108864)

  // ws regions (floats)
  float* W1   = WSF;            // [0 : 8388608)
  float* NWT  = WSF + 8388608;  // 61440
  float* TK   = WSF + 8450048;  // 524288
  float* TV   = WSF + 8974336;  // 524288
  float* ROWS = WSF + 9498624;  // 8388608
  float* WTs  = WSF + 17887232; // 262144  (sub_w^T  [512][512])
  float* WTw  = WSF + 18149376; // 262144  (word_w^T [512][512])
  float* WTq  = WSF + 18411520; // 786432  (qkv_w^T  [512][1536])
  float* ATT  = WSF;            // reuses W1 (dead after word LN)

  // 0. weight transposes (independent of activations)
  k_transpose_w<<<dim3(16, 16), 256, 0, stream>>>(sub_w, WTs, 512);
  k_transpose_w<<<dim3(16, 16), 256, 0, stream>>>(word_w, WTw, 512);
  k_transpose_w<<<dim3(48, 16), 256, 0, stream>>>(qkv_w, WTq, 1536);
  k_transpose_nw<<<240, 256, 0, stream>>>(node_w, NWT);
  // 1. embed + LN + pool2 -> FU
  k_embed<<<16384, 256, 0, stream>>>(text, pe, id_w, id_b, eg, ebeta, FU);
  // 2. GZ1 = gate(FU @ sub_w^T + b)
  k_gemm_nt<<<dim3(1024, 2), 512, 0, stream>>>(FU, WTs, sub_b, sub_th, GZ1, 512);
  // 3. W1 = pool4(LN(GZ1 + FU))  — sub never materialized
  k_add_ln_pool<<<16384, 256, 0, stream>>>(GZ1, FU, sub_ng, sub_nb, W1);
  // 4. GZ2 = gate(W1 @ word_w^T + b)
  k_gemm_nt<<<dim3(256, 2), 512, 0, stream>>>(W1, WTw, word_b, word_th, GZ2, 512);
  // 5. word = LN(GZ2 + W1) -> WD
  k_add_ln<<<4096, 256, 0, stream>>>(GZ2, W1, word_ng, word_nb, WD, 16384);
  // 6. QKV = WD @ qkv_w^T + b
  k_gemm_nt<<<dim3(256, 6), 512, 0, stream>>>(WD, WTq, qkv_b, nullptr, QKV, 1536);
  // 7. fused spiking tree -> TK, TV
  k_tree<<<1024, 256, 0, stream>>>(QKV, NWT, node_b, node_th,
                                   node_tau, node_vr, TK, TV);
  // 8. attention -> ATT (reuses dead W1 space)
  k_attn<<<32768, 256, 0, stream>>>(QKV, TK, TV, ATT);
  // 9. rows = LN(ATT + word) -> ROWS
  k_add_ln<<<4096, 256, 0, stream>>>(ATT, WD, out_ng, out_nb, ROWS, 16384);
  // 10. interpolate 512 -> 4096 rows, full fp32 d_out overwrite
  k_interp<<<32768, 256, 0, stream>>>(ROWS, O);
}